// Round 3
// baseline (14437.708 us; speedup 1.0000x reference)
//
#include <hip/hip_runtime.h>

#define B_   64
#define T_   256
#define IN_  256
#define U_   768
#define C3_  2304
#define OUT_ 64
#define NWG  256
#define NTH  1024
#define HSLOT (U_ * B_)            // 49152 floats per ring slot, layout [U][B]
#define ARR_STRIDE 128             // dwords per t: 8 groups x 16-dword (64B) lines
#define ARR_WORDS ((T_ + 1) * ARR_STRIDE)
#define WS_BYTES ((4 * HSLOT + 2 * ARR_WORDS) * 4)

// xs swizzle: float4-unit cu in row `row` lives at cu ^ (row&15) ^ ((row>>2)&12)
__device__ __forceinline__ int xswz(int cu, int row) {
  return cu ^ (row & 15) ^ ((row >> 2) & 12);
}
__device__ __forceinline__ float rdlane(float v, int lane) {
  return __uint_as_float(__builtin_amdgcn_readlane(__float_as_uint(v), lane));
}

__global__ void __launch_bounds__(NTH, 1) gru_fused(
    const float* __restrict__ x, const float* __restrict__ kern,
    const float* __restrict__ rec, const float* __restrict__ bias,
    const float* __restrict__ w_out, const float* __restrict__ b_out,
    float* __restrict__ out, float* __restrict__ ws)
{
  float* hring = ws;                                   // 4 slots x [U][B]
  unsigned* arrive = (unsigned*)(ws + 4 * HSLOT);      // [T+1][8 grp][16]
  unsigned* done   = arrive + ARR_WORDS;               // [T+1][8 grp][16]

  __shared__ float4 xs4[64 * 64];       // x[t] slice, [b][64 units] swizzled (64 KB)
  __shared__ float recpart[64][11];     // summed rec partials (ds_add), pad 11
  __shared__ float xpart[2][64][11];    // xp ring (t&1), summed via ds_add

  const int wg  = blockIdx.x;
  const int tid = threadIdx.x;
  const int l   = tid & 63;
  const int j   = __builtin_amdgcn_readfirstlane(tid >> 6);  // wave 0..15
  const int u0  = wg * 3;

  // ---- weights -> per-lane registers ----
  float wr_[9];   // rec rows: lane l<48 holds row j*48+l, 9 cols
  {
    int kr = j * 48 + (l < 48 ? l : 47);
    const float* p = rec + (size_t)kr * C3_ + u0;
    #pragma unroll
    for (int g = 0; g < 3; ++g)
      #pragma unroll
      for (int m = 0; m < 3; ++m) wr_[g * 3 + m] = p[(size_t)g * U_ + m];
  }
  float wx_[9];   // x rows: lane l<16 holds row j*16+l, 9 cols
  {
    int kx = j * 16 + (l < 16 ? l : 15);
    const float* p = kern + (size_t)kx * C3_ + u0;
    #pragma unroll
    for (int g = 0; g < 3; ++g)
      #pragma unroll
      for (int m = 0; m < 3; ++m) wx_[g * 3 + m] = p[(size_t)g * U_ + m];
  }

  // ---- gate biases (waves 0..2: thread = (b=l, u=u0+j)) ----
  float bzi=0, bri=0, bhi=0, bzr=0, brr=0, bhr=0, hreg=0.f;
  if (j < 3) {
    int u = u0 + j;
    bzi = bias[u];        bri = bias[U_ + u];        bhi = bias[2 * U_ + u];
    bzr = bias[C3_ + u];  brr = bias[C3_ + U_ + u];  bhr = bias[C3_ + 2 * U_ + u];
  }

  // ---- prologue: zero LDS partials, stage x[0], xp[0] -> xpart[0] ----
  for (int i = tid; i < 64 * 11; i += NTH) ((float*)recpart)[i] = 0.f;
  for (int i = tid; i < 2 * 64 * 11; i += NTH) ((float*)xpart)[i] = 0.f;
  #pragma unroll
  for (int p = 0; p < 4; ++p) {
    int row = p * 16 + j;
    float4 v = ((const float4*)(x + (size_t)row * T_ * IN_))[l];
    xs4[row * 64 + xswz(l, row)] = v;
  }
  __syncthreads();
  {
    float axc[9] = {0,0,0,0,0,0,0,0,0};
    #pragma unroll
    for (int kk4 = 0; kk4 < 4; ++kk4) {
      float4 xv = xs4[l * 64 + xswz(j * 4 + kk4, l)];
      #pragma unroll
      for (int s = 0; s < 4; ++s) {
        float hv = (s==0)?xv.x:(s==1)?xv.y:(s==2)?xv.z:xv.w;
        int kk = kk4 * 4 + s;
        #pragma unroll
        for (int c = 0; c < 9; ++c) axc[c] += rdlane(wx_[c], kk) * hv;
      }
    }
    #pragma unroll
    for (int c = 0; c < 9; ++c) atomicAdd(&xpart[0][l][c], axc[c]);
  }

  for (int t = 0; t < T_; ++t) {
    // ---- A: poll my producer group's arrival for h[t], then one acquire ----
    if (t > 0) {
      const unsigned* ap = arrive + (size_t)t * ARR_STRIDE + (j >> 1) * 16 + (l < 3 ? l : 0);
      unsigned need = (l < 3) ? 32u : 0u;
      while (__hip_atomic_load(ap, __ATOMIC_RELAXED, __HIP_MEMORY_SCOPE_AGENT) < need)
        __builtin_amdgcn_s_sleep(1);
      __builtin_amdgcn_fence(__ATOMIC_ACQUIRE, "agent");
    }

    // ---- B: recurrent GEMV partials (rows j*48..j*48+47 of h[t]) ----
    if (t > 0) {
      float acc[9] = {0,0,0,0,0,0,0,0,0};
      const float* hs = hring + (size_t)(t & 3) * HSLOT + (size_t)(j * 48) * 64 + l;
      #pragma unroll 6
      for (int kk = 0; kk < 48; ++kk) {
        float hv = hs[(size_t)kk * 64];
        #pragma unroll
        for (int c = 0; c < 9; ++c) acc[c] += rdlane(wr_[c], kk) * hv;
      }
      #pragma unroll
      for (int c = 0; c < 9; ++c) atomicAdd(&recpart[l][c], acc[c]);
    }
    __syncthreads();  // C

    // ---- D: done[t] add; stage x[t+1]; poll done[t-3] (slot reuse guard) ----
    if (tid == 0)
      __hip_atomic_fetch_add(done + (size_t)t * ARR_STRIDE + (wg & 7) * 16, 1u,
                             __ATOMIC_RELAXED, __HIP_MEMORY_SCOPE_AGENT);
    if (t < T_ - 1) {
      #pragma unroll
      for (int p = 0; p < 4; ++p) {
        int row = p * 16 + j;
        float4 v = ((const float4*)(x + (size_t)row * T_ * IN_ + (size_t)(t + 1) * IN_))[l];
        xs4[row * 64 + xswz(l, row)] = v;
      }
    }
    if (j == 15 && t >= 3) {
      const unsigned* dp = done + (size_t)(t - 3) * ARR_STRIDE + (l & 7) * 16;
      unsigned need = (l < 8) ? 32u : 0u;
      while (__hip_atomic_load(dp, __ATOMIC_RELAXED, __HIP_MEMORY_SCOPE_AGENT) < need)
        __builtin_amdgcn_s_sleep(1);
    }
    __syncthreads();  // E

    // ---- F: gates (waves 0..2) -> h[t+1] store + flag; then everyone xp[t+1] ----
    if (j < 3) {
      float xz = xpart[t & 1][l][j]     + bzi;
      float xr = xpart[t & 1][l][3 + j] + bri;
      float xh = xpart[t & 1][l][6 + j] + bhi;
      float iz = recpart[l][j]          + bzr;
      float ir = recpart[l][3 + j]      + brr;
      float ih = recpart[l][6 + j]      + bhr;
      float z  = 1.f / (1.f + __expf(-(xz + iz)));
      float r  = 1.f / (1.f + __expf(-(xr + ir)));
      float hh = fmaxf(0.f, xh + r * ih);          // reset_after
      float hn = z * hreg + (1.f - z) * hh;
      hreg = hn;
      hring[(size_t)((t + 1) & 3) * HSLOT + (size_t)(u0 + j) * 64 + l] = hn;
      recpart[l][j] = 0.f; recpart[l][3 + j] = 0.f; recpart[l][6 + j] = 0.f;
      xpart[t & 1][l][j] = 0.f; xpart[t & 1][l][3 + j] = 0.f; xpart[t & 1][l][6 + j] = 0.f;
      asm volatile("s_waitcnt vmcnt(0)" ::: "memory");
      __builtin_amdgcn_fence(__ATOMIC_RELEASE, "agent");
      if (l == 0)
        __hip_atomic_fetch_add(arrive + (size_t)(t + 1) * ARR_STRIDE + (wg >> 5) * 16 + j,
                               1u, __ATOMIC_RELAXED, __HIP_MEMORY_SCOPE_AGENT);
    }
    if (t < T_ - 1) {
      float axc[9] = {0,0,0,0,0,0,0,0,0};
      #pragma unroll
      for (int kk4 = 0; kk4 < 4; ++kk4) {
        float4 xv = xs4[l * 64 + xswz(j * 4 + kk4, l)];
        #pragma unroll
        for (int s = 0; s < 4; ++s) {
          float hv = (s==0)?xv.x:(s==1)?xv.y:(s==2)?xv.z:xv.w;
          int kk = kk4 * 4 + s;
          #pragma unroll
          for (int c = 0; c < 9; ++c) axc[c] += rdlane(wx_[c], kk) * hv;
        }
      }
      #pragma unroll
      for (int c = 0; c < 9; ++c) atomicAdd(&xpart[(t + 1) & 1][l][c], axc[c]);
    }
    __syncthreads();  // G
  }

  // ---- dense tail: out[b] = h[256] @ w_out + b_out ; h[256] in slot 0 ----
  if (wg < B_) {
    const unsigned* ap = arrive + (size_t)T_ * ARR_STRIDE + ((l < 24) ? ((l / 3) * 16 + (l % 3)) : 0);
    unsigned need = (l < 24) ? 32u : 0u;
    while (__hip_atomic_load(ap, __ATOMIC_RELAXED, __HIP_MEMORY_SCOPE_AGENT) < need)
      __builtin_amdgcn_s_sleep(1);
    __builtin_amdgcn_fence(__ATOMIC_ACQUIRE, "agent");
    const int o = l;
    float a = 0.f;
    for (int k = j * 48; k < j * 48 + 48; ++k)
      a += hring[(size_t)k * 64 + wg] * w_out[(size_t)k * OUT_ + o];
    float* pd = (float*)xs4;
    pd[j * 64 + o] = a;
    __syncthreads();
    if (j == 0) {
      float s = 0.f;
      #pragma unroll
      for (int p = 0; p < 16; ++p) s += pd[p * 64 + o];
      out[(size_t)wg * OUT_ + o] = s + b_out[o];
    }
  }
}

extern "C" void kernel_launch(void* const* d_in, const int* in_sizes, int n_in,
                              void* d_out, int out_size, void* d_ws, size_t ws_size,
                              hipStream_t stream) {
  const float* x     = (const float*)d_in[0];
  const float* kern  = (const float*)d_in[1];
  const float* rec   = (const float*)d_in[2];
  const float* bias  = (const float*)d_in[3];
  const float* w_out = (const float*)d_in[4];
  const float* b_out = (const float*)d_in[5];
  float* outp = (float*)d_out;
  float* ws   = (float*)d_ws;

  hipMemsetAsync(d_ws, 0, WS_BYTES, stream);   // h ring slot0 (=h0=0) + all counters

  void* args[] = {(void*)&x, (void*)&kern, (void*)&rec, (void*)&bias,
                  (void*)&w_out, (void*)&b_out, (void*)&outp, (void*)&ws};
  hipLaunchCooperativeKernel(reinterpret_cast<void*>(&gru_fused),
                             dim3(NWG), dim3(NTH), args, 0u, stream);
}

// Round 4
// 6479.486 us; speedup vs baseline: 2.2282x; 2.2282x over previous
//
#include <hip/hip_runtime.h>

#define B_   64
#define T_   256
#define IN_  256
#define U_   768
#define C3_  2304
#define OUT_ 64
#define NWG  24
#define NTH  384

#define SLOT_US    (B_ * U_)            // 49152 ushorts per h ring slot, layout [b][u]
#define SLOT_BYTES (SLOT_US * 2)        // 98304 B
#define ARR_OFF    (4 * SLOT_BYTES)     // arrive counters after 4 ring slots
#define WS_BYTES   (ARR_OFF + (T_ + 1) * 2 * 128)

typedef __bf16 bf16x8 __attribute__((ext_vector_type(8)));
typedef float  f32x16 __attribute__((ext_vector_type(16)));

__device__ __forceinline__ unsigned short f2bf(float f) {   // RNE fp32->bf16
  unsigned u = __float_as_uint(f);
  u += 0x7fff + ((u >> 16) & 1);
  return (unsigned short)(u >> 16);
}
__device__ __forceinline__ unsigned pkbf(float lo, float hi) {  // 2xf32 -> packed bf16
  unsigned r;
  asm volatile("v_cvt_pk_bf16_f32 %0, %1, %2" : "=v"(r) : "v"(lo), "v"(hi));
  return r;
}
__device__ __forceinline__ float f4get(const float4& v, int e) {
  return e == 0 ? v.x : e == 1 ? v.y : e == 2 ? v.z : v.w;
}
__device__ __forceinline__ f32x16 splat16(float v) {
  f32x16 r;
  #pragma unroll
  for (int i = 0; i < 16; ++i) r[i] = v;
  return r;
}

__global__ void __launch_bounds__(NTH, 2) gru_mfma(
    const float* __restrict__ x, const float* __restrict__ kern,
    const float* __restrict__ rec, const float* __restrict__ bias,
    const float* __restrict__ w_out, const float* __restrict__ b_out,
    float* __restrict__ out, void* __restrict__ wsv)
{
  unsigned short* ring = (unsigned short*)wsv;                  // 4 slots [64][768] bf16
  unsigned* arrive = (unsigned*)((char*)wsv + ARR_OFF);         // [(t*2+mt)*32]

  __shared__ bf16x8 B16[16 * 3 * 64];   // rec B-frags, k 0..255:  [(kk*3+g)*64+l]  48KB
  __shared__ bf16x8 XB [16 * 3 * 64];   // kern B-frags, k 0..255                   48KB
  __shared__ float4 exch[2][2][2][4][64]; // [par][mt][gate z/r][quad][lane]        32KB

  const int tid = threadIdx.x;
  const int l   = tid & 63;
  const int j   = __builtin_amdgcn_readfirstlane(tid >> 6);  // wave 0..5
  const int mt  = j & 1;        // M-half: rows mt*32..mt*32+31
  const int g   = j >> 1;       // gate 0=z 1=r 2=h
  const int wg  = blockIdx.x;
  const int u0  = wg * 32;
  const int ln  = l & 31;       // n / col-offset / C col
  const int lh  = l >> 5;       // k-half selector in fragments
  const int colg = g * U_ + u0 + ln;   // global weight column for this wave

  // ---------------- prologue: weights -> LDS frags + registers ----------------
  if (mt == 0) {
    #pragma unroll
    for (int kk = 0; kk < 16; ++kk) {
      const int kb = kk * 16 + lh * 8;
      union { bf16x8 v; unsigned short s[8]; } a, c;
      #pragma unroll
      for (int i = 0; i < 8; ++i) {
        a.s[i] = f2bf(rec [(size_t)(kb + i) * C3_ + colg]);
        c.s[i] = f2bf(kern[(size_t)(kb + i) * C3_ + colg]);
      }
      B16[(kk * 3 + g) * 64 + l] = a.v;
      XB [(kk * 3 + g) * 64 + l] = c.v;
    }
  }
  bf16x8 breg[32];                       // rec B-frags, k 256..767 (128 VGPR)
  #pragma unroll
  for (int kk = 0; kk < 32; ++kk) {
    const int kb = (kk + 16) * 16 + lh * 8;
    union { bf16x8 v; unsigned short s[8]; } a;
    #pragma unroll
    for (int i = 0; i < 8; ++i) a.s[i] = f2bf(rec[(size_t)(kb + i) * C3_ + colg]);
    breg[kk] = a.v;
  }

  // bias init vectors: g0/g1: accA = b_in+b_rec (pre-act), accX = 0
  //                    g2:    accA = b_rec_h (ih init),    accX = b_in_h (xh init)
  float biasA, biasX;
  if (g < 2) { biasA = bias[g * U_ + u0 + ln] + bias[C3_ + g * U_ + u0 + ln]; biasX = 0.f; }
  else       { biasA = bias[C3_ + 2 * U_ + u0 + ln]; biasX = bias[2 * U_ + u0 + ln]; }
  const f32x16 vbiasA = splat16(biasA), vbiasX = splat16(biasX);

  float hown[16];                        // exact fp32 carry h[b][u0+ln] (g2 uses)
  #pragma unroll
  for (int i = 0; i < 16; ++i) hown[i] = 0.f;

  const size_t rowOffB = (size_t)(mt * 32 + ln) * (U_ * 2) + lh * 16;  // ring byte offset
  const float* xb_base = x + ((size_t)(mt * 32 + ln) * T_) * IN_ + lh * 8;

  __syncthreads();   // LDS weight frags ready

  // ---------------- recurrent main loop ----------------
  for (int t = 0; t < T_; ++t) {
    f32x16 accA = vbiasA;     // rec even-kk chain (+bias)
    f32x16 accB = splat16(0.f);
    f32x16 accX = vbiasX;     // x-projection chain

    // ---- x-projection for step t (independent of h: runs in poll shadow) ----
    {
      const float* xb = xb_base + (size_t)t * IN_;
      #pragma unroll
      for (int kk = 0; kk < 16; ++kk) {
        float4 q0 = *(const float4*)(xb + kk * 16);
        float4 q1 = *(const float4*)(xb + kk * 16 + 4);
        union { bf16x8 v; unsigned u[4]; } a;
        a.u[0] = pkbf(q0.x, q0.y); a.u[1] = pkbf(q0.z, q0.w);
        a.u[2] = pkbf(q1.x, q1.y); a.u[3] = pkbf(q1.z, q1.w);
        accX = __builtin_amdgcn_mfma_f32_32x32x16_bf16(a.v, XB[(kk * 3 + g) * 64 + l], accX, 0, 0, 0);
      }
    }

    // ---- wait for h[t], then recurrent MFMAs straight from LLC ----
    if (t > 0) {
      const unsigned* ap = arrive + ((size_t)t * 2 + mt) * 32;
      while (__hip_atomic_load(ap, __ATOMIC_RELAXED, __HIP_MEMORY_SCOPE_AGENT) < NWG)
        __builtin_amdgcn_s_sleep(4);
      asm volatile("" ::: "memory");   // no reordering of h-loads above the poll

      const unsigned long long* pA =
          (const unsigned long long*)((const char*)wsv + (size_t)(t & 3) * SLOT_BYTES + rowOffB);
      #pragma unroll
      for (int kk = 0; kk < 48; ++kk) {
        union { bf16x8 v; unsigned long long u[2]; } a;
        a.u[0] = __hip_atomic_load(pA + (size_t)kk * 4,     __ATOMIC_RELAXED, __HIP_MEMORY_SCOPE_AGENT);
        a.u[1] = __hip_atomic_load(pA + (size_t)kk * 4 + 1, __ATOMIC_RELAXED, __HIP_MEMORY_SCOPE_AGENT);
        bf16x8 bv = (kk < 16) ? B16[(kk * 3 + g) * 64 + l] : breg[kk - 16];
        if (kk & 1) accB = __builtin_amdgcn_mfma_f32_32x32x16_bf16(a.v, bv, accB, 0, 0, 0);
        else        accA = __builtin_amdgcn_mfma_f32_32x32x16_bf16(a.v, bv, accA, 0, 0, 0);
      }
    }

    // ---- exchange z/r pre-activations to the gate wave ----
    const int par = t & 1;
    if (g < 2) {
      f32x16 pre = accA + accB + accX;
      #pragma unroll
      for (int q = 0; q < 4; ++q)
        exch[par][mt][g][q][l] = make_float4(pre[q * 4], pre[q * 4 + 1], pre[q * 4 + 2], pre[q * 4 + 3]);
    }
    __syncthreads();

    // ---- gate wave: nonlinearity, fp32 carry, bf16 broadcast, flag ----
    if (g == 2) {
      f32x16 crec = accA + accB;    // ih (recurrent part + b_rec_h)
      unsigned short* hst = ring + (size_t)((t + 1) & 3) * SLOT_US + (size_t)(u0 + ln);
      #pragma unroll
      for (int q = 0; q < 4; ++q) {
        float4 zp = exch[par][mt][0][q][l];
        float4 rp = exch[par][mt][1][q][l];
        #pragma unroll
        for (int e = 0; e < 4; ++e) {
          const int r = q * 4 + e;
          float z  = 1.f / (1.f + __expf(-f4get(zp, e)));
          float rr = 1.f / (1.f + __expf(-f4get(rp, e)));
          float hh = fmaxf(0.f, accX[r] + rr * crec[r]);     // reset_after
          float hn = z * hown[r] + (1.f - z) * hh;
          hown[r] = hn;
          const int b = mt * 32 + 4 * lh + (r & 3) + 8 * (r >> 2);
          __hip_atomic_store(hst + (size_t)b * U_, f2bf(hn),
                             __ATOMIC_RELAXED, __HIP_MEMORY_SCOPE_AGENT);
        }
      }
      asm volatile("s_waitcnt vmcnt(0)" ::: "memory");   // h[t+1] at LLC
      if (l == 0)
        __hip_atomic_fetch_add(arrive + ((size_t)(t + 1) * 2 + mt) * 32, 1u,
                               __ATOMIC_RELAXED, __HIP_MEMORY_SCOPE_AGENT);
    }
  }

  // ---------------- dense tail: out = h[256] @ w_out + b_out ----------------
  if (wg < 16) {
    const unsigned* a0 = arrive + ((size_t)T_ * 2) * 32;
    const unsigned* a1 = a0 + 32;
    while (__hip_atomic_load(a0, __ATOMIC_RELAXED, __HIP_MEMORY_SCOPE_AGENT) < NWG ||
           __hip_atomic_load(a1, __ATOMIC_RELAXED, __HIP_MEMORY_SCOPE_AGENT) < NWG)
      __builtin_amdgcn_s_sleep(4);
    asm volatile("" ::: "memory");

    const int o = l;                      // output column
    float acc0 = 0.f, acc1 = 0.f, acc2 = 0.f, acc3 = 0.f;
    const unsigned short* h0 = ring;      // slot (256&3)==0
    for (int k = j * 128; k < j * 128 + 128; ++k) {
      float wv = w_out[(size_t)k * OUT_ + o];
      unsigned short u0h = __hip_atomic_load(h0 + (size_t)(wg * 4 + 0) * U_ + k, __ATOMIC_RELAXED, __HIP_MEMORY_SCOPE_AGENT);
      unsigned short u1h = __hip_atomic_load(h0 + (size_t)(wg * 4 + 1) * U_ + k, __ATOMIC_RELAXED, __HIP_MEMORY_SCOPE_AGENT);
      unsigned short u2h = __hip_atomic_load(h0 + (size_t)(wg * 4 + 2) * U_ + k, __ATOMIC_RELAXED, __HIP_MEMORY_SCOPE_AGENT);
      unsigned short u3h = __hip_atomic_load(h0 + (size_t)(wg * 4 + 3) * U_ + k, __ATOMIC_RELAXED, __HIP_MEMORY_SCOPE_AGENT);
      acc0 += __uint_as_float((unsigned)u0h << 16) * wv;
      acc1 += __uint_as_float((unsigned)u1h << 16) * wv;
      acc2 += __uint_as_float((unsigned)u2h << 16) * wv;
      acc3 += __uint_as_float((unsigned)u3h << 16) * wv;
    }
    float* pd = (float*)exch;             // reuse LDS: [6 waves][4 b][64 o]
    pd[((j * 4 + 0) * 64) + o] = acc0;
    pd[((j * 4 + 1) * 64) + o] = acc1;
    pd[((j * 4 + 2) * 64) + o] = acc2;
    pd[((j * 4 + 3) * 64) + o] = acc3;
    __syncthreads();
    if (j == 0) {
      #pragma unroll
      for (int b = 0; b < 4; ++b) {
        float s = 0.f;
        #pragma unroll
        for (int w = 0; w < 6; ++w) s += pd[((w * 4 + b) * 64) + o];
        out[(size_t)(wg * 4 + b) * OUT_ + o] = s + b_out[o];
      }
    }
  }
}

extern "C" void kernel_launch(void* const* d_in, const int* in_sizes, int n_in,
                              void* d_out, int out_size, void* d_ws, size_t ws_size,
                              hipStream_t stream) {
  const float* x     = (const float*)d_in[0];
  const float* kern  = (const float*)d_in[1];
  const float* rec   = (const float*)d_in[2];
  const float* bias  = (const float*)d_in[3];
  const float* w_out = (const float*)d_in[4];
  const float* b_out = (const float*)d_in[5];
  float* outp = (float*)d_out;

  hipMemsetAsync(d_ws, 0, WS_BYTES, stream);   // h0 = 0 (bf16 zero) + all counters

  void* wsv = d_ws;
  void* args[] = {(void*)&x, (void*)&kern, (void*)&rec, (void*)&bias,
                  (void*)&w_out, (void*)&b_out, (void*)&outp, (void*)&wsv};
  hipLaunchCooperativeKernel(reinterpret_cast<void*>(&gru_mfma),
                             dim3(NWG), dim3(NTH), args, 0u, stream);
}

// Round 5
// 4394.622 us; speedup vs baseline: 3.2853x; 1.4744x over previous
//
#include <hip/hip_runtime.h>

#define B_   64
#define T_   256
#define IN_  256
#define U_   768
#define C3_  2304
#define OUT_ 64
#define NWG  24
#define NTH  384

#define SLOT_US    (B_ * U_)            // 49152 bf16 per ring slot, layout [b][u]
#define SLOT_BYTES (SLOT_US * 2)        // 98304 B
#define ARR_OFF    (4 * SLOT_BYTES)
#define WS_BYTES   (ARR_OFF + (T_ + 1) * 128)

typedef __bf16 bf16x8 __attribute__((ext_vector_type(8)));
typedef float  f32x16 __attribute__((ext_vector_type(16)));
typedef int    i32x4  __attribute__((ext_vector_type(4)));

__device__ __forceinline__ unsigned short f2bf(float f) {   // RNE fp32->bf16
  unsigned u = __float_as_uint(f);
  u += 0x7fff + ((u >> 16) & 1);
  return (unsigned short)(u >> 16);
}
__device__ __forceinline__ unsigned pkbf(float lo, float hi) {
  unsigned r;
  asm volatile("v_cvt_pk_bf16_f32 %0, %1, %2" : "=v"(r) : "v"(lo), "v"(hi));
  return r;
}
__device__ __forceinline__ f32x16 splat16(float v) {
  f32x16 r;
  #pragma unroll
  for (int i = 0; i < 16; ++i) r[i] = v;
  return r;
}

// ---- 16B cache-bypass (MALL-coherent) load/store ----
#define BYPASS_LOAD(dst, src) \
  asm volatile("global_load_dwordx4 %0, %1, off sc0 sc1" : "=v"(dst) : "v"(src))
#define BYPASS_STORE(dst, val) \
  asm volatile("global_store_dwordx4 %0, %1, off sc0 sc1" :: "v"(dst), "v"(val) : "memory")
#define WAITV8 do { asm volatile("s_waitcnt vmcnt(8)" ::: "memory"); \
                    __builtin_amdgcn_sched_barrier(0); } while (0)
#define WAITV0 do { asm volatile("s_waitcnt vmcnt(0)" ::: "memory"); \
                    __builtin_amdgcn_sched_barrier(0); } while (0)

#define ISSUE8(BUF, KB) do { \
  _Pragma("unroll") \
  for (int i_ = 0; i_ < 8; ++i_) \
    BYPASS_LOAD(BUF[i_], pbase + ((KB) + i_) * 32); \
} while (0)

#define MFMA8(BUF, KB) do { \
  _Pragma("unroll") \
  for (int i_ = 0; i_ < 8; ++i_) { \
    const int kk_ = (KB) + i_; \
    bf16x8 bv_ = recF[(kk_ * 3 + g) * 64 + l]; \
    bf16x8 av_ = __builtin_bit_cast(bf16x8, BUF[i_]); \
    if (kk_ & 1) accB = __builtin_amdgcn_mfma_f32_32x32x16_bf16(av_, bv_, accB, 0, 0, 0); \
    else         accA = __builtin_amdgcn_mfma_f32_32x32x16_bf16(av_, bv_, accA, 0, 0, 0); \
  } \
} while (0)

__global__ void __launch_bounds__(NTH, 2) gru_mfma(
    const float* __restrict__ x, const float* __restrict__ kern,
    const float* __restrict__ rec, const float* __restrict__ bias,
    const float* __restrict__ w_out, const float* __restrict__ b_out,
    float* __restrict__ out, void* __restrict__ wsv)
{
  unsigned* arrive = (unsigned*)((char*)wsv + ARR_OFF);   // [t] at stride 32 dwords

  __shared__ bf16x8 recF[48 * 3 * 64];          // rec B-frags, all K      144 KB
  __shared__ unsigned exchZR[2][2][64][8];      // packed z/r pre-acts       8 KB
  __shared__ unsigned short hstage[64 * 32];    // h[t+1] WG tile [b][u]     4 KB

  const int tid = threadIdx.x;
  const int l   = tid & 63;
  const int j   = __builtin_amdgcn_readfirstlane(tid >> 6);  // wave 0..5
  const int mt  = j & 1;         // M-half (b rows mt*32..)
  const int g   = j >> 1;        // gate 0=z 1=r 2=h
  const int wg  = blockIdx.x;
  const int u0  = wg * 32;
  const int ln  = l & 31;
  const int lh  = l >> 5;
  const int wcol = g * U_ + u0 + ln;

  // ---------------- prologue: convert weights once ----------------
  if (mt == 0) {                      // waves 0,2,4 fill rec frags for their gate
    for (int kk = 0; kk < 48; ++kk) {
      union { bf16x8 v; unsigned short s[8]; } bfr;
      #pragma unroll
      for (int i = 0; i < 8; ++i)
        bfr.s[i] = f2bf(rec[(size_t)(kk * 16 + lh * 8 + i) * C3_ + wcol]);
      recF[(kk * 3 + g) * 64 + l] = bfr.v;
    }
  }
  bf16x8 xkern[16];                   // kern frags in registers (64 VGPR)
  #pragma unroll
  for (int kk = 0; kk < 16; ++kk) {
    union { bf16x8 v; unsigned short s[8]; } bfr;
    #pragma unroll
    for (int i = 0; i < 8; ++i)
      bfr.s[i] = f2bf(kern[(size_t)(kk * 16 + lh * 8 + i) * C3_ + wcol]);
    xkern[kk] = bfr.v;
  }

  float biasA, biasX;
  if (g < 2) { biasA = bias[g * U_ + u0 + ln] + bias[C3_ + g * U_ + u0 + ln]; biasX = 0.f; }
  else       { biasA = bias[C3_ + 2 * U_ + u0 + ln]; biasX = bias[2 * U_ + u0 + ln]; }
  const f32x16 vbiasA = splat16(biasA), vbiasX = splat16(biasX);

  float hown[16];
  #pragma unroll
  for (int i = 0; i < 16; ++i) hown[i] = 0.f;

  const float* xb_base = x + (size_t)(mt * 32 + ln) * T_ * IN_ + lh * 8;
  __syncthreads();

  // ---------------- recurrent loop ----------------
  for (int t = 0; t < T_; ++t) {
    f32x16 accA = vbiasA;
    f32x16 accB = splat16(0.f);
    f32x16 accX = vbiasX;

    // x-projection for step t (independent of h — fills the poll shadow)
    {
      const float* xb = xb_base + (size_t)t * IN_;
      #pragma unroll
      for (int kk = 0; kk < 16; ++kk) {
        float4 q0 = *(const float4*)(xb + kk * 16);
        float4 q1 = *(const float4*)(xb + kk * 16 + 4);
        union { bf16x8 v; unsigned u[4]; } a;
        a.u[0] = pkbf(q0.x, q0.y); a.u[1] = pkbf(q0.z, q0.w);
        a.u[2] = pkbf(q1.x, q1.y); a.u[3] = pkbf(q1.z, q1.w);
        accX = __builtin_amdgcn_mfma_f32_32x32x16_bf16(a.v, xkern[kk], accX, 0, 0, 0);
      }
    }

    // wait for h[t], then software-pipelined bypass loads + MFMAs
    if (t > 0) {
      const unsigned* ap = arrive + (size_t)t * 32;
      while (__hip_atomic_load(ap, __ATOMIC_RELAXED, __HIP_MEMORY_SCOPE_AGENT) < NWG)
        __builtin_amdgcn_s_sleep(1);
      WAITV0;   // drain everything: vmcnt now counts only our pipeline loads

      const char* pbase = (const char*)wsv + (size_t)(t & 3) * SLOT_BYTES
                        + (size_t)(mt * 32 + ln) * (U_ * 2) + lh * 16;
      i32x4 hA0[8], hA1[8];
      ISSUE8(hA0, 0);  ISSUE8(hA1, 8);
      WAITV8; MFMA8(hA0, 0);  ISSUE8(hA0, 16);
      WAITV8; MFMA8(hA1, 8);  ISSUE8(hA1, 24);
      WAITV8; MFMA8(hA0, 16); ISSUE8(hA0, 32);
      WAITV8; MFMA8(hA1, 24); ISSUE8(hA1, 40);
      WAITV8; MFMA8(hA0, 32);
      WAITV0; MFMA8(hA1, 40);
      __builtin_amdgcn_sched_barrier(0);
    }

    // z/r waves publish packed pre-activations
    if (g < 2) {
      f32x16 pre = accA + accB + accX;
      #pragma unroll
      for (int i = 0; i < 8; ++i)
        exchZR[mt][g][l][i] = pkbf(pre[2 * i], pre[2 * i + 1]);
    }
    __syncthreads();

    // gate wave: nonlinearity + fp32 carry + bf16 tile into LDS
    if (g == 2) {
      f32x16 crec = accA + accB;
      #pragma unroll
      for (int i = 0; i < 8; ++i) {
        unsigned zw = exchZR[mt][0][l][i];
        unsigned rw = exchZR[mt][1][l][i];
        float zp[2] = { __uint_as_float(zw << 16), __uint_as_float(zw & 0xffff0000u) };
        float rp[2] = { __uint_as_float(rw << 16), __uint_as_float(rw & 0xffff0000u) };
        #pragma unroll
        for (int e = 0; e < 2; ++e) {
          const int r = 2 * i + e;
          float z  = 1.f / (1.f + __expf(-zp[e]));
          float rr = 1.f / (1.f + __expf(-rp[e]));
          float hh = fmaxf(0.f, accX[r] + rr * crec[r]);     // reset_after
          float hn = z * hown[r] + (1.f - z) * hh;
          hown[r] = hn;
          const int b = mt * 32 + 4 * lh + (r & 3) + 8 * (r >> 2);
          hstage[b * 32 + ln] = f2bf(hn);
        }
      }
    }
    __syncthreads();

    // cooperative wide store of the WG's h[t+1] tile (bypass, 16B per lane)
    if (j < 4) {
      const int row = j * 16 + (l >> 2);
      const int c   = l & 3;
      i32x4 v = *(const i32x4*)&hstage[row * 32 + c * 8];
      char* dst = (char*)wsv + (size_t)((t + 1) & 3) * SLOT_BYTES
                + (size_t)row * (U_ * 2) + (size_t)u0 * 2 + c * 16;
      BYPASS_STORE(dst, v);
    }
    asm volatile("s_waitcnt vmcnt(0)" ::: "memory");
    __syncthreads();
    if (tid == 0)
      __hip_atomic_fetch_add(arrive + (size_t)(t + 1) * 32, 1u,
                             __ATOMIC_RELAXED, __HIP_MEMORY_SCOPE_AGENT);
  }

  // ---------------- dense tail: out = h[256] @ w_out + b_out ----------------
  if (wg < 16) {
    const unsigned* ap = arrive + (size_t)T_ * 32;
    while (__hip_atomic_load(ap, __ATOMIC_RELAXED, __HIP_MEMORY_SCOPE_AGENT) < NWG)
      __builtin_amdgcn_s_sleep(2);
    asm volatile("" ::: "memory");

    i32x4* hls = (i32x4*)recF;          // reuse LDS: 384 x 16B = 4 rows of h
    {
      const int row = wg * 4 + tid / 96;      // h[256] lives in ring slot 0
      const int ck  = tid % 96;
      const char* src = (const char*)wsv + (size_t)row * (U_ * 2) + ck * 16;
      i32x4 v;
      BYPASS_LOAD(v, src);
      asm volatile("s_waitcnt vmcnt(0)" ::: "memory");
      hls[tid] = v;
    }
    __syncthreads();
    if (j < 4) {
      const int b = wg * 4 + j;
      const unsigned short* hr = (const unsigned short*)&hls[j * 96];
      float acc = 0.f;
      #pragma unroll 8
      for (int k = 0; k < U_; ++k)
        acc += __uint_as_float((unsigned)hr[k] << 16) * w_out[(size_t)k * OUT_ + l];
      out[(size_t)b * OUT_ + l] = acc + b_out[l];
    }
  }
}

extern "C" void kernel_launch(void* const* d_in, const int* in_sizes, int n_in,
                              void* d_out, int out_size, void* d_ws, size_t ws_size,
                              hipStream_t stream) {
  const float* x     = (const float*)d_in[0];
  const float* kern  = (const float*)d_in[1];
  const float* rec   = (const float*)d_in[2];
  const float* bias  = (const float*)d_in[3];
  const float* w_out = (const float*)d_in[4];
  const float* b_out = (const float*)d_in[5];
  float* outp = (float*)d_out;

  hipMemsetAsync(d_ws, 0, WS_BYTES, stream);   // h ring + arrive counters

  void* wsv = d_ws;
  void* args[] = {(void*)&x, (void*)&kern, (void*)&rec, (void*)&bias,
                  (void*)&w_out, (void*)&b_out, (void*)&outp, (void*)&wsv};
  hipLaunchCooperativeKernel(reinterpret_cast<void*>(&gru_mfma),
                             dim3(NWG), dim3(NTH), args, 0u, stream);
}

// Round 6
// 2366.708 us; speedup vs baseline: 6.1003x; 1.8568x over previous
//
#include <hip/hip_runtime.h>

#define B_   64
#define T_   256
#define IN_  256
#define U_   768
#define C3_  2304
#define OUT_ 64
#define NWG  24
#define NTH  384

// ring slot: [2 mt][48 kk][64 lane] x 16B  (B-frag order for mfma_32x32x16_bf16)
#define SLOT_BYTES (2 * 48 * 64 * 16)       // 98304
#define ARR_OFF    (4 * SLOT_BYTES)
#define WS_BYTES   (ARR_OFF + (T_ + 1) * 2 * 128)

typedef __bf16 bf16x8 __attribute__((ext_vector_type(8)));
typedef float  f32x16 __attribute__((ext_vector_type(16)));
typedef int    i32x4  __attribute__((ext_vector_type(4)));

__device__ __forceinline__ unsigned short f2bf(float f) {   // RNE fp32->bf16
  unsigned u = __float_as_uint(f);
  u += 0x7fff + ((u >> 16) & 1);
  return (unsigned short)(u >> 16);
}
__device__ __forceinline__ unsigned pkbf(float lo, float hi) {
  unsigned r;
  asm volatile("v_cvt_pk_bf16_f32 %0, %1, %2" : "=v"(r) : "v"(lo), "v"(hi));
  return r;
}

#define BYPASS_LOAD(dst, src) \
  asm volatile("global_load_dwordx4 %0, %1, off sc0 sc1" : "=v"(dst) : "v"(src))
#define BYPASS_STORE(dst, val) \
  asm volatile("global_store_dwordx4 %0, %1, off sc0 sc1" :: "v"(dst), "v"(val) : "memory")
#define WAITV8 do { asm volatile("s_waitcnt vmcnt(8)" ::: "memory"); \
                    __builtin_amdgcn_sched_barrier(0); } while (0)
#define WAITV0 do { asm volatile("s_waitcnt vmcnt(0)" ::: "memory"); \
                    __builtin_amdgcn_sched_barrier(0); } while (0)

// coalesced frag loads: lane l reads 16B at pbase + kk*1024 (pbase already +l*16)
#define ISSUE8(BUF, KB) do { \
  _Pragma("unroll") \
  for (int i_ = 0; i_ < 8; ++i_) \
    BYPASS_LOAD(BUF[i_], pbase + ((KB) + i_) * 1024); \
} while (0)

#define MFMA8(BUF, KB) do { \
  _Pragma("unroll") \
  for (int i_ = 0; i_ < 8; ++i_) { \
    bf16x8 av_ = wbase[((KB) + i_) * 64]; \
    accA = __builtin_amdgcn_mfma_f32_32x32x16_bf16( \
        av_, __builtin_bit_cast(bf16x8, BUF[i_]), accA, 0, 0, 0); \
  } \
} while (0)

__global__ void __launch_bounds__(NTH, 2) gru_mfma(
    const float* __restrict__ x, const float* __restrict__ kern,
    const float* __restrict__ rec, const float* __restrict__ bias,
    const float* __restrict__ w_out, const float* __restrict__ b_out,
    float* __restrict__ out, void* __restrict__ wsv)
{
  unsigned* arrive = (unsigned*)((char*)wsv + ARR_OFF);   // [(t*2+mt)*32]

  __shared__ bf16x8  recF[3 * 48 * 64];     // A-frags (W^T) per gate, 144 KB
  __shared__ unsigned exch[2][2][64][9];    // z/r pre-acts bf16-packed, 9 KB

  const int tid = threadIdx.x;
  const int l   = tid & 63;
  const int j   = __builtin_amdgcn_readfirstlane(tid >> 6);  // wave 0..5
  const int mt  = j & 1;          // b-half: cols mt*32..+31
  const int g   = j >> 1;         // gate 0=z 1=r 2=h
  const int wg  = blockIdx.x;
  const int u0  = wg * 32;
  const int ln  = l & 31;
  const int lh  = l >> 5;
  const bool lo = (l < 32);
  const int wcol = g * U_ + u0 + ln;

  // ---- prologue: rec W^T A-frags -> LDS (mt halves split the kk range) ----
  for (int kk = mt * 24; kk < mt * 24 + 24; ++kk) {
    union { bf16x8 v; unsigned short s[8]; } fr;
    #pragma unroll
    for (int i = 0; i < 8; ++i)
      fr.s[i] = f2bf(rec[(size_t)(kk * 16 + lh * 8 + i) * C3_ + wcol]);
    recF[(g * 48 + kk) * 64 + l] = fr.v;
  }
  bf16x8 xkern[16];                       // kern A-frags in regs (64 VGPR)
  #pragma unroll
  for (int kk = 0; kk < 16; ++kk) {
    union { bf16x8 v; unsigned short s[8]; } fr;
    #pragma unroll
    for (int i = 0; i < 8; ++i)
      fr.s[i] = f2bf(kern[(size_t)(kk * 16 + lh * 8 + i) * C3_ + wcol]);
    xkern[kk] = fr.v;
  }

  // per-reg biases (C row = u_local = (r&3)+8*(r>>2)+4*lh)
  f32x16 vbiasA, vbiasX;
  #pragma unroll
  for (int r = 0; r < 16; ++r) {
    int u = u0 + (r & 3) + 8 * (r >> 2) + 4 * lh;
    if (g < 2) { vbiasA[r] = bias[g * U_ + u] + bias[C3_ + g * U_ + u]; vbiasX[r] = 0.f; }
    else       { vbiasA[r] = bias[C3_ + 2 * U_ + u]; vbiasX[r] = bias[2 * U_ + u]; }
  }

  float hown[16];
  #pragma unroll
  for (int i = 0; i < 16; ++i) hown[i] = 0.f;

  const float*  xb_base = x + (size_t)(mt * 32 + ln) * T_ * IN_ + lh * 8;
  const bf16x8* wbase   = &recF[(g * 48) * 64 + l];
  __syncthreads();

  // ---------------- recurrent loop ----------------
  for (int t = 0; t < T_; ++t) {
    f32x16 accA = vbiasA;     // rec chain (+bias)
    f32x16 accX = vbiasX;     // x chain

    // x-projection (h-independent: fills the poll shadow)
    {
      const float* xb = xb_base + (size_t)t * IN_;
      #pragma unroll
      for (int kk = 0; kk < 16; ++kk) {
        float4 q0 = *(const float4*)(xb + kk * 16);
        float4 q1 = *(const float4*)(xb + kk * 16 + 4);
        union { bf16x8 v; unsigned u[4]; } a;
        a.u[0] = pkbf(q0.x, q0.y); a.u[1] = pkbf(q0.z, q0.w);
        a.u[2] = pkbf(q1.x, q1.y); a.u[3] = pkbf(q1.z, q1.w);
        accX = __builtin_amdgcn_mfma_f32_32x32x16_bf16(xkern[kk], a.v, accX, 0, 0, 0);
      }
    }

    // wait h[t], stream B-frags (coalesced, LLC) through MFMAs
    if (t > 0) {
      const unsigned* ap = arrive + ((size_t)t * 2 + mt) * 32;
      while (__hip_atomic_load(ap, __ATOMIC_RELAXED, __HIP_MEMORY_SCOPE_AGENT) < NWG)
        __builtin_amdgcn_s_sleep(1);
      WAITV0;

      const char* pbase = (const char*)wsv + (size_t)(t & 3) * SLOT_BYTES
                        + (size_t)mt * (48 * 1024) + (size_t)l * 16;
      i32x4 h0b[8], h1b[8];
      ISSUE8(h0b, 0);  ISSUE8(h1b, 8);
      WAITV8; MFMA8(h0b, 0);  ISSUE8(h0b, 16);
      WAITV8; MFMA8(h1b, 8);  ISSUE8(h1b, 24);
      WAITV8; MFMA8(h0b, 16); ISSUE8(h0b, 32);
      WAITV8; MFMA8(h1b, 24); ISSUE8(h1b, 40);
      WAITV8; MFMA8(h0b, 32);
      WAITV0; MFMA8(h1b, 40);
    }

    // z/r publish packed pre-activations
    if (g < 2) {
      f32x16 pre = accA + accX;
      #pragma unroll
      for (int i = 0; i < 8; ++i)
        exch[mt][g][l][i] = pkbf(pre[2 * i], pre[2 * i + 1]);
    }
    __syncthreads();                       // sync1: exch written

    unsigned zw[8], rw[8];
    if (g == 2) {
      #pragma unroll
      for (int i = 0; i < 8; ++i) { zw[i] = exch[mt][0][l][i]; rw[i] = exch[mt][1][l][i]; }
    }
    __syncthreads();                       // sync2: exch free for next t

    if (g == 2) {
      f32x16 crec = accA;                  // recurrent part + b_rec_h
      float hn[16];
      #pragma unroll
      for (int i = 0; i < 8; ++i) {
        float zf[2] = { __uint_as_float(zw[i] << 16), __uint_as_float(zw[i] & 0xffff0000u) };
        float rf[2] = { __uint_as_float(rw[i] << 16), __uint_as_float(rw[i] & 0xffff0000u) };
        #pragma unroll
        for (int e = 0; e < 2; ++e) {
          const int r = 2 * i + e;
          float z  = 1.f / (1.f + __expf(-zf[e]));
          float rr = 1.f / (1.f + __expf(-rf[e]));
          float hh = fmaxf(0.f, accX[r] + rr * crec[r]);   // reset_after
          float h  = z * hown[r] + (1.f - z) * hh;
          hown[r] = h; hn[r] = h;
        }
      }
      // pack + cross-half exchange -> two B-frags (u0..15, u16..31 for b=mt*32+ln)
      int w0 = (int)pkbf(hn[0],  hn[1]),  w1 = (int)pkbf(hn[2],  hn[3]);
      int w2 = (int)pkbf(hn[4],  hn[5]),  w3 = (int)pkbf(hn[6],  hn[7]);
      int w4 = (int)pkbf(hn[8],  hn[9]),  w5 = (int)pkbf(hn[10], hn[11]);
      int w6 = (int)pkbf(hn[12], hn[13]), w7 = (int)pkbf(hn[14], hn[15]);
      int sx0 = __shfl_xor(w0, 32, 64), sx1 = __shfl_xor(w1, 32, 64);
      int sx2 = __shfl_xor(w2, 32, 64), sx3 = __shfl_xor(w3, 32, 64);
      int sx4 = __shfl_xor(w4, 32, 64), sx5 = __shfl_xor(w5, 32, 64);
      int sx6 = __shfl_xor(w6, 32, 64), sx7 = __shfl_xor(w7, 32, 64);
      i32x4 f0, f1;
      f0[0] = lo ? w0 : sx2;  f0[1] = lo ? w1 : sx3;
      f0[2] = lo ? sx0 : w2;  f0[3] = lo ? sx1 : w3;
      f1[0] = lo ? w4 : sx6;  f1[1] = lo ? w5 : sx7;
      f1[2] = lo ? sx4 : w6;  f1[3] = lo ? sx5 : w7;

      char* dstb = (char*)wsv + (size_t)((t + 1) & 3) * SLOT_BYTES
                 + (size_t)(mt * 48 + 2 * wg) * 1024 + (size_t)l * 16;
      BYPASS_STORE(dstb, f0);
      BYPASS_STORE(dstb + 1024, f1);
      asm volatile("s_waitcnt vmcnt(0)" ::: "memory");
      if (l == 0)
        __hip_atomic_fetch_add(arrive + ((size_t)(t + 1) * 2 + mt) * 32, 1u,
                               __ATOMIC_RELAXED, __HIP_MEMORY_SCOPE_AGENT);
    }
  }

  // ---------------- dense tail: out = h[256] @ w_out + b_out (slot 0) ----------------
  if (wg < 16) {
    const unsigned* a0 = arrive + ((size_t)T_ * 2 + 0) * 32;
    const unsigned* a1 = arrive + ((size_t)T_ * 2 + 1) * 32;
    while (__hip_atomic_load(a0, __ATOMIC_RELAXED, __HIP_MEMORY_SCOPE_AGENT) < NWG ||
           __hip_atomic_load(a1, __ATOMIC_RELAXED, __HIP_MEMORY_SCOPE_AGENT) < NWG)
      __builtin_amdgcn_s_sleep(2);
    asm volatile("" ::: "memory");

    unsigned short* hrow = (unsigned short*)recF;   // reuse LDS: 4 rows x 768 bf16
    {
      const int blocal = tid / 96, c = tid % 96;
      const int kk = c >> 1, lhh = c & 1;
      const int b = wg * 4 + blocal, mtb = b >> 5, lnb = b & 31;
      const char* src = (const char*)wsv
                      + ((size_t)(mtb * 48 + kk) * 64 + lhh * 32 + lnb) * 16;
      i32x4 v;
      BYPASS_LOAD(v, src);
      asm volatile("s_waitcnt vmcnt(0)" ::: "memory");
      *(i32x4*)&hrow[blocal * 768 + kk * 16 + lhh * 8] = v;
    }
    __syncthreads();
    if (j < 4) {
      const int b = wg * 4 + j;
      float acc = 0.f;
      #pragma unroll 8
      for (int k = 0; k < U_; ++k)
        acc += __uint_as_float((unsigned)hrow[j * 768 + k] << 16)
             * w_out[(size_t)k * OUT_ + l];
      out[(size_t)b * OUT_ + l] = acc + b_out[l];
    }
  }
}

extern "C" void kernel_launch(void* const* d_in, const int* in_sizes, int n_in,
                              void* d_out, int out_size, void* d_ws, size_t ws_size,
                              hipStream_t stream) {
  const float* x     = (const float*)d_in[0];
  const float* kern  = (const float*)d_in[1];
  const float* rec   = (const float*)d_in[2];
  const float* bias  = (const float*)d_in[3];
  const float* w_out = (const float*)d_in[4];
  const float* b_out = (const float*)d_in[5];
  float* outp = (float*)d_out;

  hipMemsetAsync(d_ws, 0, WS_BYTES, stream);   // h[0]=0 + arrive counters

  void* wsv = d_ws;
  void* args[] = {(void*)&x, (void*)&kern, (void*)&rec, (void*)&bias,
                  (void*)&w_out, (void*)&b_out, (void*)&outp, (void*)&wsv};
  hipLaunchCooperativeKernel(reinterpret_cast<void*>(&gru_mfma),
                             dim3(NWG), dim3(NTH), args, 0u, stream);
}

// Round 8
// 2008.460 us; speedup vs baseline: 7.1884x; 1.1784x over previous
//
#include <hip/hip_runtime.h>

#define B_   64
#define T_   256
#define IN_  256
#define U_   768
#define C3_  2304
#define OUT_ 64
#define NWG  24
#define NTH  384

// ring slot: [2 mt][48 kk][64 lane] x 16B  (B-frag order for mfma_32x32x16_bf16)
#define SLOT_BYTES 98304u
#define ARR_OFF    (4u * SLOT_BYTES)
#define ZERO_BYTES (ARR_OFF + (T_ + 1) * 2 * 128)     // ring + arrive counters
// x B-frags: frame (t*2+mt)*16+kk, 1024 B each: lane l holds x[b=mt*32+ln][k=kk*16+lh*8..+7]
#define XFRAG_OFF  0x80000u
#define XFRAG_BYTES ((size_t)T_ * 2 * 16 * 1024)      // 8,388,608
#define WS_NEED    ((size_t)XFRAG_OFF + XFRAG_BYTES)

typedef __bf16 bf16x8 __attribute__((ext_vector_type(8)));
typedef float  f32x16 __attribute__((ext_vector_type(16)));
typedef int    i32x4  __attribute__((ext_vector_type(4)));

__device__ __forceinline__ unsigned short f2bf(float f) {   // RNE fp32->bf16
  unsigned u = __float_as_uint(f);
  u += 0x7fff + ((u >> 16) & 1);
  return (unsigned short)(u >> 16);
}
__device__ __forceinline__ unsigned pkbf(float lo, float hi) {
  unsigned r;
  asm volatile("v_cvt_pk_bf16_f32 %0, %1, %2" : "=v"(r) : "v"(lo), "v"(hi));
  return r;
}

#define BYPASS_LOAD(dst, src) \
  asm volatile("global_load_dwordx4 %0, %1, off sc0 sc1" : "=v"(dst) : "v"(src))
#define BYPASS_STORE(dst, val) \
  asm volatile("global_store_dwordx4 %0, %1, off sc0 sc1" :: "v"(dst), "v"(val) : "memory")
#define WAITV8 do { asm volatile("s_waitcnt vmcnt(8)" ::: "memory"); \
                    __builtin_amdgcn_sched_barrier(0); } while (0)
#define WAITV0 do { asm volatile("s_waitcnt vmcnt(0)" ::: "memory"); \
                    __builtin_amdgcn_sched_barrier(0); } while (0)

#define ISSUE8(BUF, KB) do { \
  _Pragma("unroll") \
  for (int i_ = 0; i_ < 8; ++i_) \
    BYPASS_LOAD(BUF[i_], pbase + ((KB) + i_) * 1024); \
} while (0)

#define MFMA8(BUF, KB) do { \
  _Pragma("unroll") \
  for (int i_ = 0; i_ < 8; ++i_) { \
    bf16x8 av_ = wbase[((KB) + i_) * 64]; \
    accA = __builtin_amdgcn_mfma_f32_32x32x16_bf16( \
        av_, __builtin_bit_cast(bf16x8, BUF[i_]), accA, 0, 0, 0); \
  } \
} while (0)

// =====================================================================
// prep: x -> MFMA B-fragment-ordered bf16 frames (run once per launch)
// =====================================================================
__global__ void __launch_bounds__(256) prep_xfrag(
    const float* __restrict__ x, void* __restrict__ wsv)
{
  __shared__ float xls[64][264];          // +8 pad: 2-way LDS aliasing only (free)
  const int t   = blockIdx.x;
  const int tid = threadIdx.x;
  const int l   = tid & 63;
  const int w   = tid >> 6;
  const int ln  = l & 31, lh = l >> 5;

  // stage x[:, t, :]: thread -> (row=tid>>2, 64 consecutive floats) = 4 full lines
  {
    const int row = tid >> 2, cb = (tid & 3) * 64;
    const float* src = x + (size_t)row * T_ * IN_ + (size_t)t * IN_ + cb;
    #pragma unroll
    for (int q = 0; q < 16; ++q)
      *(float4*)&xls[row][cb + q * 4] = *(const float4*)(src + q * 4);
  }
  __syncthreads();

  // frags: idx = w*8+s -> (mt, kk); lane l writes 8 bf16 (coalesced 16B)
  #pragma unroll
  for (int s = 0; s < 8; ++s) {
    const int idx = w * 8 + s, mt = idx >> 4, kk = idx & 15;
    const float* p = &xls[mt * 32 + ln][kk * 16 + lh * 8];
    union { bf16x8 v; unsigned u[4]; i32x4 q; } a;
    a.u[0] = pkbf(p[0], p[1]); a.u[1] = pkbf(p[2], p[3]);
    a.u[2] = pkbf(p[4], p[5]); a.u[3] = pkbf(p[6], p[7]);
    *(i32x4*)((char*)wsv + XFRAG_OFF
              + (size_t)((t * 2 + mt) * 16 + kk) * 1024 + (size_t)l * 16) = a.q;
  }
}

// =====================================================================
// main cooperative kernel: round-6 structure, x-proj fed from frags
// =====================================================================
__global__ void __launch_bounds__(NTH, 2) gru_mfma(
    const float* __restrict__ x, const float* __restrict__ kern,
    const float* __restrict__ rec, const float* __restrict__ bias,
    const float* __restrict__ w_out, const float* __restrict__ b_out,
    float* __restrict__ out, void* __restrict__ wsv)
{
  unsigned* arrive = (unsigned*)((char*)wsv + ARR_OFF);   // [(t*2+mt)*32]

  __shared__ bf16x8  recF[3 * 48 * 64];     // A-frags (W^T) per gate, 144 KB
  __shared__ unsigned exch[2][2][64][9];    // z/r pre-acts bf16-packed, 9 KB

  const int tid = threadIdx.x;
  const int l   = tid & 63;
  const int j   = __builtin_amdgcn_readfirstlane(tid >> 6);  // wave 0..5
  const int mt  = j & 1;          // b-half: cols mt*32..+31
  const int g   = j >> 1;         // gate 0=z 1=r 2=h
  const int wg  = blockIdx.x;
  const int u0  = wg * 32;
  const int ln  = l & 31;
  const int lh  = l >> 5;
  const bool lo = (l < 32);
  const int wcol = g * U_ + u0 + ln;

  // ---- prologue: rec W^T A-frags -> LDS (mt halves split the kk range) ----
  for (int kk = mt * 24; kk < mt * 24 + 24; ++kk) {
    union { bf16x8 v; unsigned short s[8]; } fr;
    #pragma unroll
    for (int i = 0; i < 8; ++i)
      fr.s[i] = f2bf(rec[(size_t)(kk * 16 + lh * 8 + i) * C3_ + wcol]);
    recF[(g * 48 + kk) * 64 + l] = fr.v;
  }
  bf16x8 xkern[16];                       // kern A-frags in regs (64 VGPR)
  #pragma unroll
  for (int kk = 0; kk < 16; ++kk) {
    union { bf16x8 v; unsigned short s[8]; } fr;
    #pragma unroll
    for (int i = 0; i < 8; ++i)
      fr.s[i] = f2bf(kern[(size_t)(kk * 16 + lh * 8 + i) * C3_ + wcol]);
    xkern[kk] = fr.v;
  }

  f32x16 vbiasA, vbiasX;
  #pragma unroll
  for (int r = 0; r < 16; ++r) {
    int u = u0 + (r & 3) + 8 * (r >> 2) + 4 * lh;
    if (g < 2) { vbiasA[r] = bias[g * U_ + u] + bias[C3_ + g * U_ + u]; vbiasX[r] = 0.f; }
    else       { vbiasA[r] = bias[C3_ + 2 * U_ + u]; vbiasX[r] = bias[2 * U_ + u]; }
  }

  float hown[16];
  #pragma unroll
  for (int i = 0; i < 16; ++i) hown[i] = 0.f;

  const bf16x8* wbase = &recF[(g * 48) * 64 + l];
  const char*   xfrg  = (const char*)wsv + XFRAG_OFF + (size_t)l * 16;
  __syncthreads();

  for (int t = 0; t < T_; ++t) {
    f32x16 accA = vbiasA;
    f32x16 accX = vbiasX;

    // ---- x-projection from precomputed frags (16 coalesced 1KB loads) ----
    {
      const char* xfb = xfrg + (size_t)((t * 2 + mt) * 16) * 1024;
      #pragma unroll
      for (int kk = 0; kk < 16; ++kk) {
        bf16x8 bv = *(const bf16x8*)(xfb + (size_t)kk * 1024);
        accX = __builtin_amdgcn_mfma_f32_32x32x16_bf16(xkern[kk], bv, accX, 0, 0, 0);
      }
    }

    // ---- wait h[t], stream B-frags (coalesced, LLC) through MFMAs ----
    if (t > 0) {
      const unsigned* ap = arrive + ((size_t)t * 2 + mt) * 32;
      while (__hip_atomic_load(ap, __ATOMIC_RELAXED, __HIP_MEMORY_SCOPE_AGENT) < NWG)
        __builtin_amdgcn_s_sleep(1);
      WAITV0;

      const char* pbase = (const char*)wsv + (size_t)(t & 3) * SLOT_BYTES
                        + (size_t)mt * (48 * 1024) + (size_t)l * 16;
      i32x4 h0b[8], h1b[8];
      ISSUE8(h0b, 0);  ISSUE8(h1b, 8);
      WAITV8; MFMA8(h0b, 0);  ISSUE8(h0b, 16);
      WAITV8; MFMA8(h1b, 8);  ISSUE8(h1b, 24);
      WAITV8; MFMA8(h0b, 16); ISSUE8(h0b, 32);
      WAITV8; MFMA8(h1b, 24); ISSUE8(h1b, 40);
      WAITV8; MFMA8(h0b, 32);
      WAITV0; MFMA8(h1b, 40);
    }

    // ---- z/r publish packed pre-activations ----
    if (g < 2) {
      f32x16 pre = accA + accX;
      #pragma unroll
      for (int i = 0; i < 8; ++i)
        exch[mt][g][l][i] = pkbf(pre[2 * i], pre[2 * i + 1]);
    }
    __syncthreads();                       // sync1: exch written

    unsigned zw[8], rw[8];
    if (g == 2) {
      #pragma unroll
      for (int i = 0; i < 8; ++i) { zw[i] = exch[mt][0][l][i]; rw[i] = exch[mt][1][l][i]; }
    }
    __syncthreads();                       // sync2: exch free for next t

    if (g == 2) {
      f32x16 crec = accA;                  // recurrent part + b_rec_h
      float hn[16];
      #pragma unroll
      for (int i = 0; i < 8; ++i) {
        float zf[2] = { __uint_as_float(zw[i] << 16), __uint_as_float(zw[i] & 0xffff0000u) };
        float rf[2] = { __uint_as_float(rw[i] << 16), __uint_as_float(rw[i] & 0xffff0000u) };
        #pragma unroll
        for (int e = 0; e < 2; ++e) {
          const int r = 2 * i + e;
          float z  = 1.f / (1.f + __expf(-zf[e]));
          float rr = 1.f / (1.f + __expf(-rf[e]));
          float hh = fmaxf(0.f, accX[r] + rr * crec[r]);   // reset_after
          float h  = z * hown[r] + (1.f - z) * hh;
          hown[r] = h; hn[r] = h;
        }
      }
      // pack + cross-half exchange -> two B-frags (b = mt*32+ln)
      int w0 = (int)pkbf(hn[0],  hn[1]),  w1 = (int)pkbf(hn[2],  hn[3]);
      int w2 = (int)pkbf(hn[4],  hn[5]),  w3 = (int)pkbf(hn[6],  hn[7]);
      int w4 = (int)pkbf(hn[8],  hn[9]),  w5 = (int)pkbf(hn[10], hn[11]);
      int w6 = (int)pkbf(hn[12], hn[13]), w7 = (int)pkbf(hn[14], hn[15]);
      int sx0 = __shfl_xor(w0, 32, 64), sx1 = __shfl_xor(w1, 32, 64);
      int sx2 = __shfl_xor(w2, 32, 64), sx3 = __shfl_xor(w3, 32, 64);
      int sx4 = __shfl_xor(w4, 32, 64), sx5 = __shfl_xor(w5, 32, 64);
      int sx6 = __shfl_xor(w6, 32, 64), sx7 = __shfl_xor(w7, 32, 64);
      i32x4 f0, f1;
      f0[0] = lo ? w0 : sx2;  f0[1] = lo ? w1 : sx3;
      f0[2] = lo ? sx0 : w2;  f0[3] = lo ? sx1 : w3;
      f1[0] = lo ? w4 : sx6;  f1[1] = lo ? w5 : sx7;
      f1[2] = lo ? sx4 : w6;  f1[3] = lo ? sx5 : w7;

      char* dstb = (char*)wsv + (size_t)((t + 1) & 3) * SLOT_BYTES
                 + (size_t)(mt * 48 + 2 * wg) * 1024 + (size_t)l * 16;
      BYPASS_STORE(dstb, f0);
      BYPASS_STORE(dstb + 1024, f1);
      asm volatile("s_waitcnt vmcnt(0)" ::: "memory");
      if (l == 0)
        __hip_atomic_fetch_add(arrive + ((size_t)(t + 1) * 2 + mt) * 32, 1u,
                               __ATOMIC_RELAXED, __HIP_MEMORY_SCOPE_AGENT);
    }
  }

  // ---- dense tail: out = h[256] @ w_out + b_out (ring slot 0) ----
  if (wg < 16) {
    const unsigned* a0 = arrive + ((size_t)T_ * 2 + 0) * 32;
    const unsigned* a1 = arrive + ((size_t)T_ * 2 + 1) * 32;
    while (__hip_atomic_load(a0, __ATOMIC_RELAXED, __HIP_MEMORY_SCOPE_AGENT) < NWG ||
           __hip_atomic_load(a1, __ATOMIC_RELAXED, __HIP_MEMORY_SCOPE_AGENT) < NWG)
      __builtin_amdgcn_s_sleep(2);
    asm volatile("" ::: "memory");

    unsigned short* hrow = (unsigned short*)recF;   // reuse LDS: 4 rows x 768 bf16
    {
      const int blocal = tid / 96, c = tid % 96;
      const int kk = c >> 1, lhh = c & 1;
      const int b = wg * 4 + blocal, mtb = b >> 5, lnb = b & 31;
      const char* src = (const char*)wsv
                      + ((size_t)(mtb * 48 + kk) * 64 + lhh * 32 + lnb) * 16;
      i32x4 v;
      BYPASS_LOAD(v, src);
      asm volatile("s_waitcnt vmcnt(0)" ::: "memory");
      *(i32x4*)&hrow[blocal * 768 + kk * 16 + lhh * 8] = v;
    }
    __syncthreads();
    if (j < 4) {
      const int b = wg * 4 + j;
      float acc = 0.f;
      #pragma unroll 8
      for (int k = 0; k < U_; ++k)
        acc += __uint_as_float((unsigned)hrow[j * 768 + k] << 16)
             * w_out[(size_t)k * OUT_ + l];
      out[(size_t)b * OUT_ + l] = acc + b_out[l];
    }
  }
}

extern "C" void kernel_launch(void* const* d_in, const int* in_sizes, int n_in,
                              void* d_out, int out_size, void* d_ws, size_t ws_size,
                              hipStream_t stream) {
  const float* x     = (const float*)d_in[0];
  const float* kern  = (const float*)d_in[1];
  const float* rec   = (const float*)d_in[2];
  const float* bias  = (const float*)d_in[3];
  const float* w_out = (const float*)d_in[4];
  const float* b_out = (const float*)d_in[5];
  float* outp = (float*)d_out;
  void* wsv   = d_ws;

  if (ws_size < WS_NEED) return;   // diagnostic: leaves out=0 (absmax==ref max)

  hipMemsetAsync(d_ws, 0, ZERO_BYTES, stream);   // ring h[0]=0 + arrive counters
  prep_xfrag<<<T_, 256, 0, stream>>>(x, d_ws);

  void* args[] = {(void*)&x, (void*)&kern, (void*)&rec, (void*)&bias,
                  (void*)&w_out, (void*)&b_out, (void*)&outp, (void*)&wsv};
  hipLaunchCooperativeKernel(reinterpret_cast<void*>(&gru_mfma),
                             dim3(NWG), dim3(NTH), args, 0u, stream);
}

// Round 10
// 1963.342 us; speedup vs baseline: 7.3536x; 1.0230x over previous
//
#include <hip/hip_runtime.h>

#define B_   64
#define T_   256
#define IN_  256
#define U_   768
#define C3_  2304
#define OUT_ 64
#define NWG  24
#define NTH  384

// ---- workspace map ----
// arrive counters at 0; ring (257 slots, NO reuse) at 0x20000; x-frags after.
#define ARR_OFF     0u
#define ARR_BYTES   0x20000u
#define RING_OFF    0x20000u
#define SLOT_STRIDE 98304u                      // [2 mt][48 kk][64 lane] x 16B
#define RING_BYTES  ((size_t)(T_ + 1) * SLOT_STRIDE)      // ~24.1 MB
#define XFRAG_OFF   0x1880000u                  // > RING_OFF + RING_BYTES
#define XFRAG_BYTES ((size_t)T_ * 2 * 16 * 1024)          // 8 MB
#define WS_NEED     ((size_t)XFRAG_OFF + XFRAG_BYTES)

typedef __bf16 bf16x8 __attribute__((ext_vector_type(8)));
typedef float  f32x16 __attribute__((ext_vector_type(16)));
typedef int    i32x4  __attribute__((ext_vector_type(4)));

__device__ __forceinline__ unsigned short f2bf(float f) {   // RNE fp32->bf16
  unsigned u = __float_as_uint(f);
  u += 0x7fff + ((u >> 16) & 1);
  return (unsigned short)(u >> 16);
}
__device__ __forceinline__ unsigned pkbf(float lo, float hi) {
  unsigned r;
  asm volatile("v_cvt_pk_bf16_f32 %0, %1, %2" : "=v"(r) : "v"(lo), "v"(hi));
  return r;
}

#define BYPASS_LOAD(dst, src) \
  asm volatile("global_load_dwordx4 %0, %1, off sc0 sc1" : "=v"(dst) : "v"(src))
#define PLAIN_LOAD(dst, src) \
  asm volatile("global_load_dwordx4 %0, %1, off" : "=v"(dst) : "v"(src))
#define BYPASS_STORE(dst, val) \
  asm volatile("global_store_dwordx4 %0, %1, off sc0 sc1" :: "v"(dst), "v"(val) : "memory")
#define WAITV8 do { asm volatile("s_waitcnt vmcnt(8)" ::: "memory"); \
                    __builtin_amdgcn_sched_barrier(0); } while (0)
#define WAITV0 do { asm volatile("s_waitcnt vmcnt(0)" ::: "memory"); \
                    __builtin_amdgcn_sched_barrier(0); } while (0)

// cached (L1/L2) coalesced frag loads: ring slot written once -> never stale
#define ISSUE8(BUF, KB) do { \
  _Pragma("unroll") \
  for (int i_ = 0; i_ < 8; ++i_) \
    PLAIN_LOAD(BUF[i_], pbase + ((KB) + i_) * 1024); \
} while (0)

#define MFMA8(BUF, KB) do { \
  _Pragma("unroll") \
  for (int i_ = 0; i_ < 8; ++i_) { \
    bf16x8 av_ = wbase[((KB) + i_) * 64]; \
    accA = __builtin_amdgcn_mfma_f32_32x32x16_bf16( \
        av_, __builtin_bit_cast(bf16x8, BUF[i_]), accA, 0, 0, 0); \
  } \
} while (0)

// =====================================================================
// prep: x -> MFMA B-fragment-ordered bf16 frames (validated round 8)
// =====================================================================
__global__ void __launch_bounds__(256) prep_xfrag(
    const float* __restrict__ x, void* __restrict__ wsv)
{
  __shared__ float xls[64][264];
  const int t   = blockIdx.x;
  const int tid = threadIdx.x;
  const int l   = tid & 63;
  const int w   = tid >> 6;
  const int ln  = l & 31, lh = l >> 5;
  {
    const int row = tid >> 2, cb = (tid & 3) * 64;
    const float* src = x + (size_t)row * T_ * IN_ + (size_t)t * IN_ + cb;
    #pragma unroll
    for (int q = 0; q < 16; ++q)
      *(float4*)&xls[row][cb + q * 4] = *(const float4*)(src + q * 4);
  }
  __syncthreads();
  #pragma unroll
  for (int s = 0; s < 8; ++s) {
    const int idx = w * 8 + s, mt = idx >> 4, kk = idx & 15;
    const float* p = &xls[mt * 32 + ln][kk * 16 + lh * 8];
    union { bf16x8 v; unsigned u[4]; i32x4 q; } a;
    a.u[0] = pkbf(p[0], p[1]); a.u[1] = pkbf(p[2], p[3]);
    a.u[2] = pkbf(p[4], p[5]); a.u[3] = pkbf(p[6], p[7]);
    *(i32x4*)((char*)wsv + XFRAG_OFF
              + (size_t)((t * 2 + mt) * 16 + kk) * 1024 + (size_t)l * 16) = a.q;
  }
}

// =====================================================================
// main cooperative kernel: round-8 structure, no-reuse ring, cached loads
// =====================================================================
__global__ void __launch_bounds__(NTH, 2) gru_mfma(
    const float* __restrict__ x, const float* __restrict__ kern,
    const float* __restrict__ rec, const float* __restrict__ bias,
    const float* __restrict__ w_out, const float* __restrict__ b_out,
    float* __restrict__ out, void* __restrict__ wsv)
{
  unsigned* arrive = (unsigned*)((char*)wsv + ARR_OFF);   // [(t*2+mt)*32]
  char*     ring   = (char*)wsv + RING_OFF;

  __shared__ bf16x8  recF[3 * 48 * 64];     // A-frags (W^T) per gate, 144 KB
  __shared__ unsigned exch[2][2][64][9];    // z/r pre-acts bf16-packed, 9 KB

  const int tid = threadIdx.x;
  const int l   = tid & 63;
  const int j   = __builtin_amdgcn_readfirstlane(tid >> 6);  // wave 0..5
  const int mt  = j & 1;          // b-half: cols mt*32..+31
  const int g   = j >> 1;         // gate 0=z 1=r 2=h
  const int wg  = blockIdx.x;
  const int u0  = wg * 32;
  const int ln  = l & 31;
  const int lh  = l >> 5;
  const bool lo = (l < 32);
  const int wcol = g * U_ + u0 + ln;

  // ---- prologue: rec W^T A-frags -> LDS (mt halves split the kk range) ----
  for (int kk = mt * 24; kk < mt * 24 + 24; ++kk) {
    union { bf16x8 v; unsigned short s[8]; } fr;
    #pragma unroll
    for (int i = 0; i < 8; ++i)
      fr.s[i] = f2bf(rec[(size_t)(kk * 16 + lh * 8 + i) * C3_ + wcol]);
    recF[(g * 48 + kk) * 64 + l] = fr.v;
  }
  bf16x8 xkern[16];                       // kern A-frags in regs (64 VGPR)
  #pragma unroll
  for (int kk = 0; kk < 16; ++kk) {
    union { bf16x8 v; unsigned short s[8]; } fr;
    #pragma unroll
    for (int i = 0; i < 8; ++i)
      fr.s[i] = f2bf(kern[(size_t)(kk * 16 + lh * 8 + i) * C3_ + wcol]);
    xkern[kk] = fr.v;
  }

  f32x16 vbiasA, vbiasX;
  #pragma unroll
  for (int r = 0; r < 16; ++r) {
    int u = u0 + (r & 3) + 8 * (r >> 2) + 4 * lh;
    if (g < 2) { vbiasA[r] = bias[g * U_ + u] + bias[C3_ + g * U_ + u]; vbiasX[r] = 0.f; }
    else       { vbiasA[r] = bias[C3_ + 2 * U_ + u]; vbiasX[r] = bias[2 * U_ + u]; }
  }

  float hown[16];
  #pragma unroll
  for (int i = 0; i < 16; ++i) hown[i] = 0.f;

  const bf16x8* wbase = &recF[(g * 48) * 64 + l];
  const char*   xfrg  = (const char*)wsv + XFRAG_OFF + (size_t)l * 16;
  __syncthreads();

  for (int t = 0; t < T_; ++t) {
    f32x16 accA = vbiasA;
    f32x16 accX = vbiasX;

    // ---- x-projection from precomputed frags (cached; fills poll shadow) ----
    {
      const char* xfb = xfrg + (size_t)((t * 2 + mt) * 16) * 1024;
      #pragma unroll
      for (int kk = 0; kk < 16; ++kk) {
        bf16x8 bv = *(const bf16x8*)(xfb + (size_t)kk * 1024);
        accX = __builtin_amdgcn_mfma_f32_32x32x16_bf16(xkern[kk], bv, accX, 0, 0, 0);
      }
    }

    // ---- wait h[t], stream 48 cached B-frags through MFMAs ----
    if (t > 0) {
      const unsigned* ap = arrive + ((size_t)t * 2 + mt) * 32;
      while (__hip_atomic_load(ap, __ATOMIC_RELAXED, __HIP_MEMORY_SCOPE_AGENT) < NWG)
        __builtin_amdgcn_s_sleep(1);
      WAITV0;

      const char* pbase = ring + (size_t)t * SLOT_STRIDE
                        + (size_t)mt * (48 * 1024) + (size_t)l * 16;
      i32x4 h0b[8], h1b[8];
      ISSUE8(h0b, 0);  ISSUE8(h1b, 8);
      WAITV8; MFMA8(h0b, 0);  ISSUE8(h0b, 16);
      WAITV8; MFMA8(h1b, 8);  ISSUE8(h1b, 24);
      WAITV8; MFMA8(h0b, 16); ISSUE8(h0b, 32);
      WAITV8; MFMA8(h1b, 24); ISSUE8(h1b, 40);
      WAITV8; MFMA8(h0b, 32);
      WAITV0; MFMA8(h1b, 40);
    }

    // ---- z/r publish packed pre-activations ----
    if (g < 2) {
      f32x16 pre = accA + accX;
      #pragma unroll
      for (int i = 0; i < 8; ++i)
        exch[mt][g][l][i] = pkbf(pre[2 * i], pre[2 * i + 1]);
    }
    __syncthreads();                       // sync1: exch written

    unsigned zw[8], rw[8];
    if (g == 2) {
      #pragma unroll
      for (int i = 0; i < 8; ++i) { zw[i] = exch[mt][0][l][i]; rw[i] = exch[mt][1][l][i]; }
    }
    __syncthreads();                       // sync2: exch free for next t

    if (g == 2) {
      f32x16 crec = accA;                  // recurrent part + b_rec_h
      float hn[16];
      #pragma unroll
      for (int i = 0; i < 8; ++i) {
        float zf[2] = { __uint_as_float(zw[i] << 16), __uint_as_float(zw[i] & 0xffff0000u) };
        float rf[2] = { __uint_as_float(rw[i] << 16), __uint_as_float(rw[i] & 0xffff0000u) };
        #pragma unroll
        for (int e = 0; e < 2; ++e) {
          const int r = 2 * i + e;
          float z  = 1.f / (1.f + __expf(-zf[e]));
          float rr = 1.f / (1.f + __expf(-rf[e]));
          float hh = fmaxf(0.f, accX[r] + rr * crec[r]);   // reset_after
          float h  = z * hown[r] + (1.f - z) * hh;
          hown[r] = h; hn[r] = h;
        }
      }
      // pack + cross-half exchange -> two B-frags (b = mt*32+ln)
      int w0 = (int)pkbf(hn[0],  hn[1]),  w1 = (int)pkbf(hn[2],  hn[3]);
      int w2 = (int)pkbf(hn[4],  hn[5]),  w3 = (int)pkbf(hn[6],  hn[7]);
      int w4 = (int)pkbf(hn[8],  hn[9]),  w5 = (int)pkbf(hn[10], hn[11]);
      int w6 = (int)pkbf(hn[12], hn[13]), w7 = (int)pkbf(hn[14], hn[15]);
      int sx0 = __shfl_xor(w0, 32, 64), sx1 = __shfl_xor(w1, 32, 64);
      int sx2 = __shfl_xor(w2, 32, 64), sx3 = __shfl_xor(w3, 32, 64);
      int sx4 = __shfl_xor(w4, 32, 64), sx5 = __shfl_xor(w5, 32, 64);
      int sx6 = __shfl_xor(w6, 32, 64), sx7 = __shfl_xor(w7, 32, 64);
      i32x4 f0, f1;
      f0[0] = lo ? w0 : sx2;  f0[1] = lo ? w1 : sx3;
      f0[2] = lo ? sx0 : w2;  f0[3] = lo ? sx1 : w3;
      f1[0] = lo ? w4 : sx6;  f1[1] = lo ? w5 : sx7;
      f1[2] = lo ? sx4 : w6;  f1[3] = lo ? sx5 : w7;

      char* dstb = ring + (size_t)(t + 1) * SLOT_STRIDE
                 + (size_t)(mt * 48 + 2 * wg) * 1024 + (size_t)l * 16;
      BYPASS_STORE(dstb, f0);
      BYPASS_STORE(dstb + 1024, f1);
      asm volatile("s_waitcnt vmcnt(0)" ::: "memory");
      if (l == 0)
        __hip_atomic_fetch_add(arrive + ((size_t)(t + 1) * 2 + mt) * 32, 1u,
                               __ATOMIC_RELAXED, __HIP_MEMORY_SCOPE_AGENT);
    }
  }

  // ---- dense tail: out = h[256] @ w_out + b_out (slot 256) ----
  if (wg < 16) {
    const unsigned* a0 = arrive + ((size_t)T_ * 2 + 0) * 32;
    const unsigned* a1 = arrive + ((size_t)T_ * 2 + 1) * 32;
    while (__hip_atomic_load(a0, __ATOMIC_RELAXED, __HIP_MEMORY_SCOPE_AGENT) < NWG ||
           __hip_atomic_load(a1, __ATOMIC_RELAXED, __HIP_MEMORY_SCOPE_AGENT) < NWG)
      __builtin_amdgcn_s_sleep(2);
    asm volatile("" ::: "memory");

    unsigned short* hrow = (unsigned short*)recF;   // reuse LDS: 4 rows x 768 bf16
    {
      const int blocal = tid / 96, c = tid % 96;
      const int kk = c >> 1, lhh = c & 1;
      const int b = wg * 4 + blocal, mtb = b >> 5, lnb = b & 31;
      const char* src = ring + (size_t)T_ * SLOT_STRIDE
                      + (size_t)(mtb * 48 + kk) * 1024 + (size_t)(lhh * 32 + lnb) * 16;
      i32x4 v;
      BYPASS_LOAD(v, src);
      asm volatile("s_waitcnt vmcnt(0)" ::: "memory");
      *(i32x4*)&hrow[blocal * 768 + kk * 16 + lhh * 8] = v;
    }
    __syncthreads();
    if (j < 4) {
      const int b = wg * 4 + j;
      float acc = 0.f;
      #pragma unroll 8
      for (int k = 0; k < U_; ++k)
        acc += __uint_as_float((unsigned)hrow[j * 768 + k] << 16)
             * w_out[(size_t)k * OUT_ + l];
      out[(size_t)b * OUT_ + l] = acc + b_out[l];
    }
  }
}

extern "C" void kernel_launch(void* const* d_in, const int* in_sizes, int n_in,
                              void* d_out, int out_size, void* d_ws, size_t ws_size,
                              hipStream_t stream) {
  const float* x     = (const float*)d_in[0];
  const float* kern  = (const float*)d_in[1];
  const float* rec   = (const float*)d_in[2];
  const float* bias  = (const float*)d_in[3];
  const float* w_out = (const float*)d_in[4];
  const float* b_out = (const float*)d_in[5];
  float* outp = (float*)d_out;
  void* wsv   = d_ws;

  if (ws_size < WS_NEED) return;

  hipMemsetAsync(d_ws, 0, ARR_BYTES, stream);    // arrive counters
  prep_xfrag<<<T_, 256, 0, stream>>>(x, d_ws);

  void* args[] = {(void*)&x, (void*)&kern, (void*)&rec, (void*)&bias,
                  (void*)&w_out, (void*)&b_out, (void*)&outp, (void*)&wsv};
  hipLaunchCooperativeKernel(reinterpret_cast<void*>(&gru_mfma),
                             dim3(NWG), dim3(NTH), args, 0u, stream);
}

// Round 12
// 1957.134 us; speedup vs baseline: 7.3770x; 1.0032x over previous
//
#include <hip/hip_runtime.h>

#define B_   64
#define T_   256
#define IN_  256
#define U_   768
#define C3_  2304
#define OUT_ 64
#define NWG  24
#define NTH  384
#define GRID 256           // claim grid: 1 WG/CU; 24 same-XCD WGs self-select

// ---- workspace map ----
#define ARR_OFF     0u
#define ARR_BYTES   0x20000u
#define CLAIM_OFF   0x18000u
#define RING_OFF    0x20000u
#define SLOT_STRIDE 98304u                      // [2 mt][48 kk][64 lane] x 16B
#define RING_BYTES  ((size_t)(T_ + 1) * SLOT_STRIDE)      // ~24.1 MB
#define XFRAG_OFF   0x1880000u
#define XFRAG_BYTES ((size_t)T_ * 2 * 16 * 1024)          // 8 MB
#define WS_NEED     ((size_t)XFRAG_OFF + XFRAG_BYTES)

// s_getreg imm for HW_REG_XCC_ID (id=20, offset=0, size=32) [verified m09]
#define XCC_GETREG_IMM ((31 << 11) | (0 << 6) | 20)

typedef __bf16 bf16x8 __attribute__((ext_vector_type(8)));
typedef float  f32x16 __attribute__((ext_vector_type(16)));
typedef int    i32x4  __attribute__((ext_vector_type(4)));

__device__ __forceinline__ unsigned short f2bf(float f) {   // RNE fp32->bf16
  unsigned u = __float_as_uint(f);
  u += 0x7fff + ((u >> 16) & 1);
  return (unsigned short)(u >> 16);
}
__device__ __forceinline__ unsigned pkbf(float lo, float hi) {
  unsigned r;
  asm volatile("v_cvt_pk_bf16_f32 %0, %1, %2" : "=v"(r) : "v"(lo), "v"(hi));
  return r;
}

#define PLAIN_LOAD(dst, src) \
  asm volatile("global_load_dwordx4 %0, %1, off" : "=v"(dst) : "v"(src))
#define PLAIN_STORE(dst, val) \
  asm volatile("global_store_dwordx4 %0, %1, off" :: "v"(dst), "v"(val) : "memory")
#define WAITV8 do { asm volatile("s_waitcnt vmcnt(8)" ::: "memory"); \
                    __builtin_amdgcn_sched_barrier(0); } while (0)
#define WAITV0 do { asm volatile("s_waitcnt vmcnt(0)" ::: "memory"); \
                    __builtin_amdgcn_sched_barrier(0); } while (0)

#define ISSUE8(BUF, KB) do { \
  _Pragma("unroll") \
  for (int i_ = 0; i_ < 8; ++i_) \
    PLAIN_LOAD(BUF[i_], pbase + ((KB) + i_) * 1024); \
} while (0)

#define MFMA8(BUF, KB) do { \
  _Pragma("unroll") \
  for (int i_ = 0; i_ < 8; ++i_) { \
    bf16x8 av_ = wbase[((KB) + i_) * 64]; \
    accA = __builtin_amdgcn_mfma_f32_32x32x16_bf16( \
        av_, __builtin_bit_cast(bf16x8, BUF[i_]), accA, 0, 0, 0); \
  } \
} while (0)

// =====================================================================
// prep: x -> MFMA B-fragment-ordered bf16 frames (validated round 8/10)
// =====================================================================
__global__ void __launch_bounds__(256) prep_xfrag(
    const float* __restrict__ x, void* __restrict__ wsv)
{
  __shared__ float xls[64][264];
  const int t   = blockIdx.x;
  const int tid = threadIdx.x;
  const int l   = tid & 63;
  const int w   = tid >> 6;
  const int ln  = l & 31, lh = l >> 5;
  {
    const int row = tid >> 2, cb = (tid & 3) * 64;
    const float* src = x + (size_t)row * T_ * IN_ + (size_t)t * IN_ + cb;
    #pragma unroll
    for (int q = 0; q < 16; ++q)
      *(float4*)&xls[row][cb + q * 4] = *(const float4*)(src + q * 4);
  }
  __syncthreads();
  #pragma unroll
  for (int s = 0; s < 8; ++s) {
    const int idx = w * 8 + s, mt = idx >> 4, kk = idx & 15;
    const float* p = &xls[mt * 32 + ln][kk * 16 + lh * 8];
    union { bf16x8 v; unsigned u[4]; i32x4 q; } a;
    a.u[0] = pkbf(p[0], p[1]); a.u[1] = pkbf(p[2], p[3]);
    a.u[2] = pkbf(p[4], p[5]); a.u[3] = pkbf(p[6], p[7]);
    *(i32x4*)((char*)wsv + XFRAG_OFF
              + (size_t)((t * 2 + mt) * 16 + kk) * 1024 + (size_t)l * 16) = a.q;
  }
}

// =====================================================================
// main: round-10 protocol, 24 workers self-selected onto ONE XCD;
// h exchange via the XCD-coherent L2 (plain stores; AGENT-scope polls)
// =====================================================================
__global__ void __launch_bounds__(NTH, 2) gru_mfma(
    const float* __restrict__ x, const float* __restrict__ kern,
    const float* __restrict__ rec, const float* __restrict__ bias,
    const float* __restrict__ w_out, const float* __restrict__ b_out,
    float* __restrict__ out, void* __restrict__ wsv)
{
  unsigned* arrive = (unsigned*)((char*)wsv + ARR_OFF);   // [(t*2+mt)*32]
  unsigned* claim  = (unsigned*)((char*)wsv + CLAIM_OFF); // [0..7]=per-XCD, [16]=winner
  char*     ring   = (char*)wsv + RING_OFF;

  __shared__ bf16x8  recF[3 * 48 * 64];     // A-frags (W^T) per gate, 144 KB
  __shared__ unsigned exch[2][2][64][9];    // z/r pre-acts bf16-packed, 9 KB
  __shared__ unsigned s_role;

  // ---- one-XCD claim (cross-XCD machinery at LLC; one-time) ----
  if (threadIdx.x == 0) {
    unsigned xcc = __builtin_amdgcn_s_getreg(XCC_GETREG_IMM) & 7u;
    unsigned tk = __hip_atomic_fetch_add(&claim[xcc], 1u,
                                         __ATOMIC_RELAXED, __HIP_MEMORY_SCOPE_AGENT);
    if (tk == 23u) {                        // 24th arrival crowns this XCD
      unsigned exp = 0u;
      __hip_atomic_compare_exchange_strong(&claim[16], &exp, xcc + 1u,
          __ATOMIC_RELAXED, __ATOMIC_RELAXED, __HIP_MEMORY_SCOPE_AGENT);
    }
    unsigned w;
    while ((w = __hip_atomic_load(&claim[16], __ATOMIC_RELAXED,
                                  __HIP_MEMORY_SCOPE_AGENT)) == 0u)
      __builtin_amdgcn_s_sleep(2);
    s_role = (xcc == w - 1u && tk < 24u) ? tk : 0xFFFFFFFFu;
  }
  __syncthreads();
  const unsigned role = s_role;
  if (role == 0xFFFFFFFFu) return;          // not a worker

  const int tid = threadIdx.x;
  const int l   = tid & 63;
  const int j   = __builtin_amdgcn_readfirstlane(tid >> 6);  // wave 0..5
  const int mt  = j & 1;          // b-half: cols mt*32..+31
  const int g   = j >> 1;         // gate 0=z 1=r 2=h
  const int wg  = (int)role;      // logical WG id 0..23
  const int u0  = wg * 32;
  const int ln  = l & 31;
  const int lh  = l >> 5;
  const bool lo = (l < 32);
  const int wcol = g * U_ + u0 + ln;

  // ---- prologue: rec W^T A-frags -> LDS (mt halves split the kk range) ----
  for (int kk = mt * 24; kk < mt * 24 + 24; ++kk) {
    union { bf16x8 v; unsigned short s[8]; } fr;
    #pragma unroll
    for (int i = 0; i < 8; ++i)
      fr.s[i] = f2bf(rec[(size_t)(kk * 16 + lh * 8 + i) * C3_ + wcol]);
    recF[(g * 48 + kk) * 64 + l] = fr.v;
  }
  bf16x8 xkern[16];                       // kern A-frags in regs (64 VGPR)
  #pragma unroll
  for (int kk = 0; kk < 16; ++kk) {
    union { bf16x8 v; unsigned short s[8]; } fr;
    #pragma unroll
    for (int i = 0; i < 8; ++i)
      fr.s[i] = f2bf(kern[(size_t)(kk * 16 + lh * 8 + i) * C3_ + wcol]);
    xkern[kk] = fr.v;
  }

  f32x16 vbiasA, vbiasX;
  #pragma unroll
  for (int r = 0; r < 16; ++r) {
    int u = u0 + (r & 3) + 8 * (r >> 2) + 4 * lh;
    if (g < 2) { vbiasA[r] = bias[g * U_ + u] + bias[C3_ + g * U_ + u]; vbiasX[r] = 0.f; }
    else       { vbiasA[r] = bias[C3_ + 2 * U_ + u]; vbiasX[r] = bias[2 * U_ + u]; }
  }

  float hown[16];
  #pragma unroll
  for (int i = 0; i < 16; ++i) hown[i] = 0.f;

  const bf16x8* wbase = &recF[(g * 48) * 64 + l];
  const char*   xfrg  = (const char*)wsv + XFRAG_OFF + (size_t)l * 16;
  __syncthreads();

  for (int t = 0; t < T_; ++t) {
    f32x16 accA = vbiasA;
    f32x16 accX = vbiasX;

    // ---- x-projection from precomputed frags (fills poll shadow) ----
    {
      const char* xfb = xfrg + (size_t)((t * 2 + mt) * 16) * 1024;
      #pragma unroll
      for (int kk = 0; kk < 16; ++kk) {
        bf16x8 bv = *(const bf16x8*)(xfb + (size_t)kk * 1024);
        accX = __builtin_amdgcn_mfma_f32_32x32x16_bf16(xkern[kk], bv, accX, 0, 0, 0);
      }
    }

    // ---- wait h[t] (AGENT-scope poll, L1-bypassing), stream L2 B-frags ----
    if (t > 0) {
      const unsigned* ap = arrive + ((size_t)t * 2 + mt) * 32;
      while (__hip_atomic_load(ap, __ATOMIC_RELAXED, __HIP_MEMORY_SCOPE_AGENT) < NWG)
        __builtin_amdgcn_s_sleep(1);
      WAITV0;

      const char* pbase = ring + (size_t)t * SLOT_STRIDE
                        + (size_t)mt * (48 * 1024) + (size_t)l * 16;
      i32x4 h0b[8], h1b[8];
      ISSUE8(h0b, 0);  ISSUE8(h1b, 8);
      WAITV8; MFMA8(h0b, 0);  ISSUE8(h0b, 16);
      WAITV8; MFMA8(h1b, 8);  ISSUE8(h1b, 24);
      WAITV8; MFMA8(h0b, 16); ISSUE8(h0b, 32);
      WAITV8; MFMA8(h1b, 24); ISSUE8(h1b, 40);
      WAITV8; MFMA8(h0b, 32);
      WAITV0; MFMA8(h1b, 40);
    }

    // ---- z/r publish packed pre-activations ----
    if (g < 2) {
      f32x16 pre = accA + accX;
      #pragma unroll
      for (int i = 0; i < 8; ++i)
        exch[mt][g][l][i] = pkbf(pre[2 * i], pre[2 * i + 1]);
    }
    __syncthreads();                       // sync1: exch written

    unsigned zw[8], rw[8];
    if (g == 2) {
      #pragma unroll
      for (int i = 0; i < 8; ++i) { zw[i] = exch[mt][0][l][i]; rw[i] = exch[mt][1][l][i]; }
    }
    __syncthreads();                       // sync2: exch free for next t

    if (g == 2) {
      f32x16 crec = accA;                  // recurrent part + b_rec_h
      float hn[16];
      #pragma unroll
      for (int i = 0; i < 8; ++i) {
        float zf[2] = { __uint_as_float(zw[i] << 16), __uint_as_float(zw[i] & 0xffff0000u) };
        float rf[2] = { __uint_as_float(rw[i] << 16), __uint_as_float(rw[i] & 0xffff0000u) };
        #pragma unroll
        for (int e = 0; e < 2; ++e) {
          const int r = 2 * i + e;
          float z  = 1.f / (1.f + __expf(-zf[e]));
          float rr = 1.f / (1.f + __expf(-rf[e]));
          float hh = fmaxf(0.f, accX[r] + rr * crec[r]);   // reset_after
          float h  = z * hown[r] + (1.f - z) * hh;
          hown[r] = h; hn[r] = h;
        }
      }
      // pack + cross-half exchange -> two B-frags (b = mt*32+ln)
      int w0 = (int)pkbf(hn[0],  hn[1]),  w1 = (int)pkbf(hn[2],  hn[3]);
      int w2 = (int)pkbf(hn[4],  hn[5]),  w3 = (int)pkbf(hn[6],  hn[7]);
      int w4 = (int)pkbf(hn[8],  hn[9]),  w5 = (int)pkbf(hn[10], hn[11]);
      int w6 = (int)pkbf(hn[12], hn[13]), w7 = (int)pkbf(hn[14], hn[15]);
      int sx0 = __shfl_xor(w0, 32, 64), sx1 = __shfl_xor(w1, 32, 64);
      int sx2 = __shfl_xor(w2, 32, 64), sx3 = __shfl_xor(w3, 32, 64);
      int sx4 = __shfl_xor(w4, 32, 64), sx5 = __shfl_xor(w5, 32, 64);
      int sx6 = __shfl_xor(w6, 32, 64), sx7 = __shfl_xor(w7, 32, 64);
      i32x4 f0, f1;
      f0[0] = lo ? w0 : sx2;  f0[1] = lo ? w1 : sx3;
      f0[2] = lo ? sx0 : w2;  f0[3] = lo ? sx1 : w3;
      f1[0] = lo ? w4 : sx6;  f1[1] = lo ? w5 : sx7;
      f1[2] = lo ? sx4 : w6;  f1[3] = lo ? sx5 : w7;

      char* dstb = ring + (size_t)(t + 1) * SLOT_STRIDE
                 + (size_t)(mt * 48 + 2 * wg) * 1024 + (size_t)l * 16;
      PLAIN_STORE(dstb, f0);               // write-through L1 -> XCD L2
      PLAIN_STORE(dstb + 1024, f1);
      asm volatile("s_waitcnt vmcnt(0)" ::: "memory");   // data at L2
      if (l == 0)
        __hip_atomic_fetch_add(arrive + ((size_t)(t + 1) * 2 + mt) * 32, 1u,
                               __ATOMIC_RELAXED, __HIP_MEMORY_SCOPE_AGENT);
    }
  }

  // ---- dense tail: out = h[256] @ w_out + b_out (slot 256, L2) ----
  if (wg < 16) {
    const unsigned* a0 = arrive + ((size_t)T_ * 2 + 0) * 32;
    const unsigned* a1 = arrive + ((size_t)T_ * 2 + 1) * 32;
    while (__hip_atomic_load(a0, __ATOMIC_RELAXED, __HIP_MEMORY_SCOPE_AGENT) < NWG ||
           __hip_atomic_load(a1, __ATOMIC_RELAXED, __HIP_MEMORY_SCOPE_AGENT) < NWG)
      __builtin_amdgcn_s_sleep(2);
    asm volatile("" ::: "memory");

    unsigned short* hrow = (unsigned short*)recF;   // reuse LDS: 4 rows x 768 bf16
    {
      const int blocal = tid / 96, c = tid % 96;
      const int kk = c >> 1, lhh = c & 1;
      const int b = wg * 4 + blocal, mtb = b >> 5, lnb = b & 31;
      const char* src = ring + (size_t)T_ * SLOT_STRIDE
                      + (size_t)(mtb * 48 + kk) * 1024 + (size_t)(lhh * 32 + lnb) * 16;
      i32x4 v;
      PLAIN_LOAD(v, src);
      asm volatile("s_waitcnt vmcnt(0)" ::: "memory");
      *(i32x4*)&hrow[blocal * 768 + kk * 16 + lhh * 8] = v;
    }
    __syncthreads();
    if (j < 4) {
      const int b = wg * 4 + j;
      float acc = 0.f;
      #pragma unroll 8
      for (int k = 0; k < U_; ++k)
        acc += __uint_as_float((unsigned)hrow[j * 768 + k] << 16)
             * w_out[(size_t)k * OUT_ + l];
      out[(size_t)b * OUT_ + l] = acc + b_out[l];
    }
  }
}

extern "C" void kernel_launch(void* const* d_in, const int* in_sizes, int n_in,
                              void* d_out, int out_size, void* d_ws, size_t ws_size,
                              hipStream_t stream) {
  const float* x     = (const float*)d_in[0];
  const float* kern  = (const float*)d_in[1];
  const float* rec   = (const float*)d_in[2];
  const float* bias  = (const float*)d_in[3];
  const float* w_out = (const float*)d_in[4];
  const float* b_out = (const float*)d_in[5];
  float* outp = (float*)d_out;
  void* wsv   = d_ws;

  if (ws_size < WS_NEED) return;

  hipMemsetAsync(d_ws, 0, ARR_BYTES, stream);    // arrive flags + claim words
  prep_xfrag<<<T_, 256, 0, stream>>>(x, d_ws);

  void* args[] = {(void*)&x, (void*)&kern, (void*)&rec, (void*)&bias,
                  (void*)&w_out, (void*)&b_out, (void*)&outp, (void*)&wsv};
  hipLaunchCooperativeKernel(reinterpret_cast<void*>(&gru_mfma),
                             dim3(GRID), dim3(NTH), args, 0u, stream);
}